// Round 12
// baseline (396.514 us; speedup 1.0000x reference)
//
#include <hip/hip_runtime.h>
#include <hip/hip_fp16.h>
#include <math.h>

#define PI_F 3.14159265358979323846f
#define ROWB 2112ull            // bytes per arena row
#define IMGB (ROWB * 256ull)    // 540672 bytes per image

__device__ __forceinline__ unsigned rev8(unsigned v){ return __brev(v) >> 24; }

__device__ __forceinline__ float2 cmulf(float2 a, float2 b){ return make_float2(a.x*b.x - a.y*b.y, a.x*b.y + a.y*b.x); }
__device__ __forceinline__ float2 cmulc(float2 a, float2 b){ return make_float2(a.x*b.x + a.y*b.y, a.y*b.x - a.x*b.y); } // a*conj(b)
__device__ __forceinline__ float2 cadd (float2 a, float2 b){ return make_float2(a.x+b.x, a.y+b.y); }
__device__ __forceinline__ float2 csub (float2 a, float2 b){ return make_float2(a.x-b.x, a.y-b.y); }
__device__ __forceinline__ float2 eix(float a){ float s, c; __sincosf(a, &s, &c); return make_float2(c, s); }
__device__ __forceinline__ float2 sx(float2 v, int d){ return make_float2(__shfl_xor(v.x, d), __shfl_xor(v.y, d)); }

__device__ __forceinline__ float frcp(float x){ float r; asm("v_rcp_f32 %0, %1" : "=v"(r) : "v"(x)); return r; }

// atan2(y,x) for y > 0 (result in (0, pi)). Deg-11 odd minimax, err ~2e-6 rad.
__device__ __forceinline__ float fast_atan2pos(float y, float x){
  const float ax = fabsf(x);
  const float mn = fminf(ax, y), mx = fmaxf(ax, y);
  const float t  = mn * frcp(mx);
  const float z  = t * t;
  float p = -0.01172120f;
  p = fmaf(p, z,  0.05265332f);
  p = fmaf(p, z, -0.11643287f);
  p = fmaf(p, z,  0.19354346f);
  p = fmaf(p, z, -0.33262347f);
  p = fmaf(p, z,  0.99997726f);
  p = p * t;
  p = (y > ax) ? (1.57079632679f - p) : p;
  p = (x < 0.f) ? (3.14159265359f - p) : p;
  return p;
}

__device__ __forceinline__ unsigned packh2u(float a, float b){
  return __builtin_bit_cast(unsigned, __floats2half2_rn(a, b));
}
__device__ __forceinline__ float2 unpackh2(float p){
  return __half22float2(__builtin_bit_cast(__half2, p));
}

// Per-lane twiddles (forward sign e^{-i...}); inverse uses conjugates via cmulc.
// PROVEN CORRECT (rounds 4/5/7 benches).
struct Twid { float2 w, w2, t[6]; };
__device__ __forceinline__ void mktw(Twid& T, int lane){
  T.w  = eix(-(2.0f * PI_F / 256.0f) * (float)lane);
  T.w2 = cmulf(T.w, T.w);
  #pragma unroll
  for (int st = 0; st < 6; ++st){
    const int d = 32 >> st;
    T.t[st] = eix(-(PI_F / (float)d) * (float)(lane & (d - 1)));  // W_{2d}^{lane mod d}
  }
}

// Forward 256-pt DIF. In: v[s] = x[lane+64s] (natural). Out: position p=lane+64s holds X[rev8(p)].
__device__ __forceinline__ void fft256_fwd(float2 v[4], int lane, const Twid& T){
  const float2 t0 = cadd(v[0], v[2]);
  const float2 b0 = cmulf(csub(v[0], v[2]), T.w);
  const float2 t1 = cadd(v[1], v[3]);
  const float2 w64 = make_float2(T.w.y, -T.w.x);           // w * (-i)
  const float2 b1 = cmulf(csub(v[1], v[3]), w64);
  v[0] = cadd(t0, t1);
  v[1] = cmulf(csub(t0, t1), T.w2);
  v[2] = cadd(b0, b1);
  v[3] = cmulf(csub(b0, b1), T.w2);
  #pragma unroll
  for (int st = 0; st < 6; ++st){
    const int d = 32 >> st;
    const float2 tw = T.t[st];
    const bool hi = (lane & d) != 0;
    #pragma unroll
    for (int s = 0; s < 4; ++s){
      const float2 p  = sx(v[s], d);
      const float2 bo = cmulf(csub(p, v[s]), tw);
      const float2 lo = cadd(v[s], p);
      v[s] = hi ? bo : lo;
    }
  }
}

// DUAL inverse 256-pt DIT (unnormalized): two independent streams interleaved per stage
// for 8-wide ILP (hides shuffle latency). Arithmetic per element identical to the proven
// single-stream form. In: position p holds Y[rev8(p)]. Out: v[s] = y[lane+64s].
__device__ __forceinline__ void fft256_inv2(float2 a[4], float2 b[4], int lane, const Twid& T){
  #pragma unroll
  for (int st = 0; st < 6; ++st){
    const int d = 1 << st;
    const float2 tw = T.t[5 - st];                          // conj applied via cmulc
    const bool hi = (lane & d) != 0;
    #pragma unroll
    for (int s = 0; s < 4; ++s){
      const float2 pa = sx(a[s], d);
      const float2 pb = sx(b[s], d);
      const float2 ma = cmulc(hi ? a[s] : pa, tw);
      const float2 mb = cmulc(hi ? b[s] : pb, tw);
      a[s] = hi ? csub(pa, ma) : cadd(a[s], ma);
      b[s] = hi ? csub(pb, mb) : cadd(b[s], mb);
    }
  }
  const float2 uci = make_float2(T.w.y, T.w.x);             // conj(w)*i
  {
    const float2 m1 = cmulc(a[1], T.w2);
    const float2 m3a = cmulc(a[3], T.w2);
    const float2 n0 = cadd(a[0], m1), n1 = csub(a[0], m1);
    const float2 n2 = cadd(a[2], m3a), n3 = csub(a[2], m3a);
    const float2 m2 = cmulc(n2, T.w);
    const float2 m3 = cmulf(n3, uci);
    a[0] = cadd(n0, m2); a[2] = csub(n0, m2);
    a[1] = cadd(n1, m3); a[3] = csub(n1, m3);
  }
  {
    const float2 m1 = cmulc(b[1], T.w2);
    const float2 m3a = cmulc(b[3], T.w2);
    const float2 n0 = cadd(b[0], m1), n1 = csub(b[0], m1);
    const float2 n2 = cadd(b[2], m3a), n3 = csub(b[2], m3a);
    const float2 m2 = cmulc(n2, T.w);
    const float2 m3 = cmulf(n3, uci);
    b[0] = cadd(n0, m2); b[2] = csub(n0, m2);
    b[1] = cadd(n1, m3); b[3] = csub(n1, m3);
  }
}

// K0: scrambled Riesz scale table + zero row.
__global__ __launch_bounds__(256) void k0_prep(const float* __restrict__ km,
                                               float* __restrict__ sTabS,
                                               float* __restrict__ zrow){
  const int idx = blockIdx.x * 256 + threadIdx.x;
  const int q = idx >> 8, r = idx & 255;
  const int u = rev8(q), v = rev8(r);
  const float kv = km[u * 256 + v];
  float sp = fmaxf(kv, 0.f) + log1pf(expf(-fabsf(kv)));
  sp = fminf(fmaxf(sp, 1e-3f), 10.f);
  const float fu = (float)(u + 1), fv = (float)(v + 1);
  sTabS[idx] = sp / (sqrtf(fu * fu + fv * fv) + 1e-6f) * (1.0f / 65536.0f);
  if (blockIdx.x == 0){
    zrow[threadIdx.x] = 0.f;
    zrow[threadIdx.x + 256] = 0.f;
    if (threadIdx.x < 16) zrow[threadIdx.x + 512] = 0.f;
  }
}

// K1: forward row FFT. 4 rows/block (1 per wave). No LDS, no barriers.
__global__ __launch_bounds__(256) void k1_row(const float* __restrict__ x, char* __restrict__ arena){
  const int grp = threadIdx.x >> 6, lane = threadIdx.x & 63;
  const int rs = blockIdx.x * 4 + grp;
  Twid T; mktw(T, lane);
  const float* xr = x + (size_t)rs * 256;
  float2 v[4];
  #pragma unroll
  for (int s = 0; s < 4; ++s) v[s] = make_float2(xr[lane + 64 * s], 0.f);
  fft256_fwd(v, lane, T);
  float2* S = (float2*)(arena + (size_t)rs * ROWB);
  #pragma unroll
  for (int s = 0; s < 4; ++s) S[lane + 64 * s] = v[s];
}

// K2: per (image, 8-col tile): col FFT, both Riesz filters, dual col IFFT; packed fp16 in place.
// Single proven 9-pitch swizzled LDS buffer. Per-column LDS slots are wave-private (XOR swizzle
// bijective per row) and reads precede writes in program order -> in-place writeback, only the
// staging barriers remain.
__global__ __launch_bounds__(256) void k2_col(char* __restrict__ arena, const float* __restrict__ sTabS){
  __shared__ float2 lds[256 * 9];
  const int tid = threadIdx.x;
  const int b  = blockIdx.x >> 5;
  const int u0 = (blockIdx.x & 31) << 3;
  char* base = arena + (size_t)b * IMGB;

  #pragma unroll
  for (int k = 0; k < 8; ++k){
    const int idx = tid + (k << 8);
    const int r = idx >> 3, cc = idx & 7;
    lds[r * 9 + (cc ^ ((r >> 3) & 7))] = *(const float2*)(base + (size_t)r * ROWB + (size_t)(u0 + cc) * 8);
  }
  __syncthreads();

  const int wv = tid >> 6, lane = tid & 63;
  Twid T; mktw(T, lane);
  const int r6 = __brev(lane) >> 26;                 // rev6(lane)
  float fvv[4];
  fvv[0] = (float)(4 * r6 + 0 + 1);
  fvv[1] = (float)(4 * r6 + 2 + 1);
  fvv[2] = (float)(4 * r6 + 1 + 1);
  fvv[3] = (float)(4 * r6 + 3 + 1);
  const int swb = (lane >> 3) & 7;

  #pragma unroll
  for (int cp = 0; cp < 2; ++cp){
    const int c = wv * 2 + cp;
    const int q = u0 + c;
    const int swc = c ^ swb;
    float2 F[4];
    #pragma unroll
    for (int s = 0; s < 4; ++s) F[s] = lds[(lane + 64 * s) * 9 + swc];
    fft256_fwd(F, lane, T);
    float sc[4];
    #pragma unroll
    for (int s = 0; s < 4; ++s) sc[s] = sTabS[q * 256 + lane + 64 * s];
    const float fu = (float)(rev8((unsigned)q) + 1);
    float2 G1[4], G2[4];
    #pragma unroll
    for (int s = 0; s < 4; ++s){
      const float a1 = fvv[s] * sc[s];
      const float a2 = fu * sc[s];
      G1[s] = make_float2(a1 * F[s].y, -a1 * F[s].x);
      G2[s] = make_float2(a2 * F[s].y, -a2 * F[s].x);
    }
    fft256_inv2(G1, G2, lane, T);
    #pragma unroll
    for (int s = 0; s < 4; ++s)
      lds[(lane + 64 * s) * 9 + swc] =
          make_float2(__uint_as_float(packh2u(G1[s].x, G1[s].y)),
                      __uint_as_float(packh2u(G2[s].x, G2[s].y)));
  }
  __syncthreads();
  #pragma unroll
  for (int k = 0; k < 8; ++k){
    const int idx = tid + (k << 8);
    const int r = idx >> 3, cc = idx & 7;
    *(float2*)(base + (size_t)r * ROWB + (size_t)(u0 + cc) * 8) = lds[r * 9 + (cc ^ ((r >> 3) & 7))];
  }
}

// K3: dual row IFFT of packed U1/U2 + pointwise; writes A (f32) + PT (h2) in place over SPEC rows.
// Per-row sum of A_boost -> rowsum[rs] (plain store; atomics were a measured 100 µs regression).
__global__ __launch_bounds__(256) void k3_rowinv(const float* __restrict__ x, char* __restrict__ arena,
    const float* __restrict__ ampw, const float* __restrict__ ampb,
    float* __restrict__ rowsum){
  const int grp = threadIdx.x >> 6, lane = threadIdx.x & 63;
  const int rs = blockIdx.x * 4 + grp;
  Twid T; mktw(T, lane);
  char* rowb = arena + (size_t)rs * ROWB;
  float2 g1[4], g2[4];
  #pragma unroll
  for (int s = 0; s < 4; ++s){
    const float2 pk = *(const float2*)(rowb + (size_t)(lane + 64 * s) * 8);
    g1[s] = unpackh2(pk.x); g2[s] = unpackh2(pk.y);
  }
  fft256_inv2(g1, g2, lane, T);
  const float aw = *ampw, ab = *ampb;
  const float* xr = x + (size_t)rs * 256;
  float* Arow = (float*)(rowb + 16);
  unsigned* Prow = (unsigned*)(rowb + 1072);
  float sum = 0.f;
  #pragma unroll
  for (int s = 0; s < 4; ++s){
    const int j = lane + 64 * s;
    const float xv = xr[j];
    const float R1 = sqrtf(fmaf(g1[s].x, g1[s].x, g1[s].y * g1[s].y)) + 1e-6f;
    const float R2 = sqrtf(fmaf(g2[s].x, g2[s].x, g2[s].y * g2[s].y)) + 1e-6f;
    const float rr = fmaf(R1, R1, R2 * R2);
    const float A = sqrtf(fmaxf(fmaf(xv, xv, rr), 0.f) + 1e-6f);
    const float P  = fast_atan2pos(sqrtf(rr) + 1e-6f, xv + 1e-6f);
    const float Th = fast_atan2pos(R2, R1 + 1e-6f);
    const float Ab = A + fmaxf(fmaf(aw, A, ab), 0.f);
    Arow[j] = Ab;
    Prow[j] = packh2u(P, Th);
    sum += Ab;
  }
  #pragma unroll
  for (int off = 32; off; off >>= 1) sum += __shfl_down(sum, off);
  if (lane == 0) rowsum[rs] = sum;
}

// KPAD: zero column halos of A and PT segments (one image per block, one row per thread).
__global__ __launch_bounds__(256) void kpad(char* __restrict__ arena){
  char* row = arena + (size_t)blockIdx.x * IMGB + (size_t)threadIdx.x * ROWB;
  const float4 z = make_float4(0.f, 0.f, 0.f, 0.f);
  *(float4*)(row)         = z;   // A cols -4..-1
  *(float4*)(row + 1040)  = z;   // A cols 256..259
  *(float4*)(row + 1056)  = z;   // PT cols -4..-1
  *(float4*)(row + 2096)  = z;   // PT cols 256..259
}

// K4: per-image gate from 256 row sums. One block per image.
__global__ __launch_bounds__(256) void k4_gw(const float* __restrict__ rowsum,
    const float* __restrict__ fc1w, const float* __restrict__ fc1b,
    const float* __restrict__ fc2w, const float* __restrict__ fc2b,
    float* __restrict__ gw){
  __shared__ float red[256];
  const int tid = threadIdx.x;
  red[tid] = rowsum[blockIdx.x * 256 + tid];
  __syncthreads();
  #pragma unroll
  for (int off = 128; off; off >>= 1){
    if (tid < off) red[tid] += red[tid + off];
    __syncthreads();
  }
  if (tid == 0){
    const float gf = red[0] * (1.0f / 65536.0f);
    float acc = fc2b[0];
    #pragma unroll
    for (int k = 0; k < 16; ++k)
      acc += fc2w[k] * fmaxf(gf * fc1w[k] + fc1b[k], 0.f);
    gw[blockIdx.x] = frcp(1.f + __expf(-acc));
  }
}

// K5: register-blocked 4x4/thread convs + fusion; row-halo via zero-row pointer.
__global__ __launch_bounds__(256) void k5_fuse(
    const char* __restrict__ arena, const float* __restrict__ zrowf,
    const float* __restrict__ gwp,
    const float* __restrict__ theta_w, const float* __restrict__ theta_b,
    const float* __restrict__ phase_w, const float* __restrict__ phase_b,
    const float* __restrict__ phase_gamma, const float* __restrict__ phase_beta,
    const float* __restrict__ phase_mean, const float* __restrict__ phase_var,
    const float* __restrict__ ms_w1, const float* __restrict__ ms_b1,
    const float* __restrict__ ms_w2, const float* __restrict__ ms_b2,
    const float* __restrict__ ms_w3, const float* __restrict__ ms_b3,
    const float* __restrict__ fin_w, const float* __restrict__ fin_b,
    const float* __restrict__ fin_gamma, const float* __restrict__ fin_beta,
    const float* __restrict__ fin_mean, const float* __restrict__ fin_var,
    float* __restrict__ out){
  const int z = blockIdx.z;
  const int tx = threadIdx.x & 15, ty = threadIdx.x >> 4;
  const int j0 = (blockIdx.x << 6) + (tx << 2);
  const int i0 = (blockIdx.y << 6) + (ty << 2);
  const char* img = arena + (size_t)z * IMGB;

  float tw9[9], pw9[9], w1[9], w2[9], w3[9];
  #pragma unroll
  for (int k = 0; k < 9; ++k){
    tw9[k] = theta_w[k]; pw9[k] = phase_w[k];
    w1[k] = ms_w1[k]; w2[k] = ms_w2[k]; w3[k] = ms_w3[k];
  }
  const float b1s = ms_b1[0], b2s = ms_b2[0], b3s = ms_b3[0];
  const float tbs = theta_b[0], pbs = phase_b[0];

  float4 m1[4], m2[4], m3[4], at[4], ap[4], Ac[4], Tc[4];
  #pragma unroll
  for (int oi = 0; oi < 4; ++oi){
    m1[oi] = make_float4(b1s, b1s, b1s, b1s);
    m2[oi] = make_float4(b2s, b2s, b2s, b2s);
    m3[oi] = make_float4(b3s, b3s, b3s, b3s);
    at[oi] = make_float4(tbs, tbs, tbs, tbs);
    ap[oi] = make_float4(pbs, pbs, pbs, pbs);
  }

  // ---- A-plane (rows i0-3 .. i0+6, cols j0-4 .. j0+7) ----
  #pragma unroll
  for (int lr = 0; lr < 10; ++lr){
    const int ar = i0 - 3 + lr;
    const float* rowA = ((unsigned)ar < 256u) ? (const float*)(img + (size_t)ar * ROWB) : zrowf;
    const float4 va = *(const float4*)(rowA + j0);
    const float4 vb = *(const float4*)(rowA + j0 + 4);
    const float4 vc = *(const float4*)(rowA + j0 + 8);
    const float a[12] = {va.x, va.y, va.z, va.w, vb.x, vb.y, vb.z, vb.w, vc.x, vc.y, vc.z, vc.w};
    #pragma unroll
    for (int oi = 0; oi < 4; ++oi){
      const int dd = lr - 3 - oi;
      if (dd >= -1 && dd <= 1){
        const int wr = (dd + 1) * 3;
        #pragma unroll
        for (int dx = -1; dx <= 1; ++dx){
          const float w = w1[wr + dx + 1];
          m1[oi].x += w * a[4 + 0 + dx]; m1[oi].y += w * a[4 + 1 + dx];
          m1[oi].z += w * a[4 + 2 + dx]; m1[oi].w += w * a[4 + 3 + dx];
        }
      }
      if (dd == -2 || dd == 0 || dd == 2){
        const int wr = (dd / 2 + 1) * 3;
        #pragma unroll
        for (int dx = -1; dx <= 1; ++dx){
          const float w = w2[wr + dx + 1];
          m2[oi].x += w * a[4 + 0 + 2 * dx]; m2[oi].y += w * a[4 + 1 + 2 * dx];
          m2[oi].z += w * a[4 + 2 + 2 * dx]; m2[oi].w += w * a[4 + 3 + 2 * dx];
        }
      }
      if (dd == -3 || dd == 0 || dd == 3){
        const int wr = (dd / 3 + 1) * 3;
        #pragma unroll
        for (int dx = -1; dx <= 1; ++dx){
          const float w = w3[wr + dx + 1];
          m3[oi].x += w * a[4 + 0 + 3 * dx]; m3[oi].y += w * a[4 + 1 + 3 * dx];
          m3[oi].z += w * a[4 + 2 + 3 * dx]; m3[oi].w += w * a[4 + 3 + 3 * dx];
        }
      }
      if (dd == 0) Ac[oi] = make_float4(a[4], a[5], a[6], a[7]);
    }
  }

  // ---- PT-plane (rows i0-1 .. i0+4) ----
  #pragma unroll
  for (int lr = 0; lr < 6; ++lr){
    const int ar = i0 - 1 + lr;
    const unsigned* rowP = ((unsigned)ar < 256u) ? (const unsigned*)(img + (size_t)ar * ROWB + 1056)
                                                 : (const unsigned*)zrowf;
    const uint4 ua = *(const uint4*)(rowP + j0);
    const uint4 ub = *(const uint4*)(rowP + j0 + 4);
    const uint4 uc = *(const uint4*)(rowP + j0 + 8);
    const unsigned uu[12] = {ua.x, ua.y, ua.z, ua.w, ub.x, ub.y, ub.z, ub.w, uc.x, uc.y, uc.z, uc.w};
    float p[12], t[12];
    #pragma unroll
    for (int k = 0; k < 12; ++k){
      const float2 pt = unpackh2(__builtin_bit_cast(float, uu[k]));
      p[k] = pt.x; t[k] = pt.y;
    }
    #pragma unroll
    for (int oi = 0; oi < 4; ++oi){
      const int dd = lr - 1 - oi;
      if (dd >= -1 && dd <= 1){
        const int wr = (dd + 1) * 3;
        #pragma unroll
        for (int dx = -1; dx <= 1; ++dx){
          const float wp = pw9[wr + dx + 1], wt = tw9[wr + dx + 1];
          ap[oi].x += wp * p[4 + 0 + dx]; ap[oi].y += wp * p[4 + 1 + dx];
          ap[oi].z += wp * p[4 + 2 + dx]; ap[oi].w += wp * p[4 + 3 + dx];
          at[oi].x += wt * t[4 + 0 + dx]; at[oi].y += wt * t[4 + 1 + dx];
          at[oi].z += wt * t[4 + 2 + dx]; at[oi].w += wt * t[4 + 3 + dx];
        }
      }
      if (dd == 0) Tc[oi] = make_float4(t[4], t[5], t[6], t[7]);
    }
  }

  // ---- epilogue ----
  const float gwb = gwp[z];
  const float inv_p = phase_gamma[0] * rsqrtf(phase_var[0] + 1e-5f);
  const float pmean = phase_mean[0], pbeta = phase_beta[0];
  const float f0 = fin_w[0], f1 = fin_w[1], f2 = fin_w[2];
  const float f3 = fin_w[3], f4 = fin_w[4], f5 = fin_w[5];
  const float fb = fin_b[0];
  const float inv_f = fin_gamma[0] * rsqrtf(fin_var[0] + 1e-5f);
  const float fmean = fin_mean[0], fbeta = fin_beta[0];

  #pragma unroll
  for (int oi = 0; oi < 4; ++oi){
    const float mm1[4] = {m1[oi].x, m1[oi].y, m1[oi].z, m1[oi].w};
    const float mm2[4] = {m2[oi].x, m2[oi].y, m2[oi].z, m2[oi].w};
    const float mm3[4] = {m3[oi].x, m3[oi].y, m3[oi].z, m3[oi].w};
    const float tt[4]  = {at[oi].x, at[oi].y, at[oi].z, at[oi].w};
    const float pp[4]  = {ap[oi].x, ap[oi].y, ap[oi].z, ap[oi].w};
    const float ac[4]  = {Ac[oi].x, Ac[oi].y, Ac[oi].z, Ac[oi].w};
    const float tc[4]  = {Tc[oi].x, Tc[oi].y, Tc[oi].z, Tc[oi].w};
    float o4[4];
    #pragma unroll
    for (int oj = 0; oj < 4; ++oj){
      const float Gt = tc[oj] * frcp(1.f + __expf(-tt[oj]));
      const float Pp = fmaxf((pp[oj] - pmean) * inv_p + pbeta, 0.f);
      const float pre = f0 * ac[oj] + f1 * Pp + f2 * Gt
                      + gwb * (f3 * mm1[oj] + f4 * mm2[oj] + f5 * mm3[oj]) + fb;
      float o = (pre - fmean) * inv_f + fbeta;
      o4[oj] = fminf(fmaxf(o, 0.f), 1.f);
    }
    *(float4*)(out + ((size_t)(z * 256 + i0 + oi) << 8) + j0) = make_float4(o4[0], o4[1], o4[2], o4[3]);
  }
}

extern "C" void kernel_launch(void* const* d_in, const int* in_sizes, int n_in,
                              void* d_out, int out_size, void* d_ws, size_t ws_size,
                              hipStream_t stream){
  const float* x  = (const float*)d_in[0];
  const float* km = (const float*)d_in[1];

  // layout: [arena: imgsPer*IMGB] [zrow 2112] [sTabS 262144] [gw 1024] [rowsum rowsPer*4]
  int N = 1;
  while (N < 64){
    const size_t need = (size_t)(256 / N) * IMGB + 2112ull + 262144ull + 1024ull
                      + (size_t)(256 / N) * 1024ull;
    if (need <= ws_size) break;
    N <<= 1;
  }
  const int imgsPer = 256 / N;
  const int rowsPer = imgsPer * 256;

  char*  ws     = (char*)d_ws;
  char*  arena  = ws;
  float* zrow   = (float*)(ws + (size_t)imgsPer * IMGB);
  float* sTabS  = (float*)(ws + (size_t)imgsPer * IMGB + 2112ull);
  float* gwbuf  = (float*)(ws + (size_t)imgsPer * IMGB + 2112ull + 262144ull);
  float* rowsum = (float*)(ws + (size_t)imgsPer * IMGB + 2112ull + 262144ull + 1024ull);

  k0_prep<<<256, 256, 0, stream>>>(km, sTabS, zrow);

  for (int s = 0; s < N; ++s){
    const float* xs = x + (size_t)s * rowsPer * 256;
    float* outs = (float*)d_out + (size_t)s * rowsPer * 256;

    k1_row<<<rowsPer / 4, 256, 0, stream>>>(xs, arena);
    k2_col<<<imgsPer * 32, 256, 0, stream>>>(arena, sTabS);
    k3_rowinv<<<rowsPer / 4, 256, 0, stream>>>(xs, arena,
        (const float*)d_in[10], (const float*)d_in[11], rowsum);
    kpad<<<imgsPer, 256, 0, stream>>>(arena);
    k4_gw<<<imgsPer, 256, 0, stream>>>(rowsum,
        (const float*)d_in[18], (const float*)d_in[19],
        (const float*)d_in[20], (const float*)d_in[21], gwbuf);
    k5_fuse<<<dim3(4, 4, imgsPer), 256, 0, stream>>>(
        arena, zrow, gwbuf,
        (const float*)d_in[2],  (const float*)d_in[3],
        (const float*)d_in[4],  (const float*)d_in[5],
        (const float*)d_in[6],  (const float*)d_in[7],
        (const float*)d_in[8],  (const float*)d_in[9],
        (const float*)d_in[12], (const float*)d_in[13],
        (const float*)d_in[14], (const float*)d_in[15],
        (const float*)d_in[16], (const float*)d_in[17],
        (const float*)d_in[22], (const float*)d_in[23],
        (const float*)d_in[24], (const float*)d_in[25],
        (const float*)d_in[26], (const float*)d_in[27],
        outs);
  }
}

// Round 13
// 378.090 us; speedup vs baseline: 1.0487x; 1.0487x over previous
//
#include <hip/hip_runtime.h>
#include <hip/hip_fp16.h>
#include <math.h>

#define PI_F 3.14159265358979323846f
#define ROWB 2112ull            // bytes per arena row
#define IMGB (ROWB * 256ull)    // 540672 bytes per image

__device__ __forceinline__ unsigned rev8(unsigned v){ return __brev(v) >> 24; }

__device__ __forceinline__ float2 cmulf(float2 a, float2 b){ return make_float2(a.x*b.x - a.y*b.y, a.x*b.y + a.y*b.x); }
__device__ __forceinline__ float2 cmulc(float2 a, float2 b){ return make_float2(a.x*b.x + a.y*b.y, a.y*b.x - a.x*b.y); } // a*conj(b)
__device__ __forceinline__ float2 cadd (float2 a, float2 b){ return make_float2(a.x+b.x, a.y+b.y); }
__device__ __forceinline__ float2 csub (float2 a, float2 b){ return make_float2(a.x-b.x, a.y-b.y); }
__device__ __forceinline__ float2 eix(float a){ float s, c; __sincosf(a, &s, &c); return make_float2(c, s); }
__device__ __forceinline__ float2 sx(float2 v, int d){ return make_float2(__shfl_xor(v.x, d), __shfl_xor(v.y, d)); }

__device__ __forceinline__ float frcp(float x){ float r; asm("v_rcp_f32 %0, %1" : "=v"(r) : "v"(x)); return r; }

// atan2(y,x) for y > 0 (result in (0, pi)). Deg-11 odd minimax, err ~2e-6 rad.
__device__ __forceinline__ float fast_atan2pos(float y, float x){
  const float ax = fabsf(x);
  const float mn = fminf(ax, y), mx = fmaxf(ax, y);
  const float t  = mn * frcp(mx);
  const float z  = t * t;
  float p = -0.01172120f;
  p = fmaf(p, z,  0.05265332f);
  p = fmaf(p, z, -0.11643287f);
  p = fmaf(p, z,  0.19354346f);
  p = fmaf(p, z, -0.33262347f);
  p = fmaf(p, z,  0.99997726f);
  p = p * t;
  p = (y > ax) ? (1.57079632679f - p) : p;
  p = (x < 0.f) ? (3.14159265359f - p) : p;
  return p;
}

__device__ __forceinline__ unsigned packh2u(float a, float b){
  return __builtin_bit_cast(unsigned, __floats2half2_rn(a, b));
}
__device__ __forceinline__ float2 unpackh2(float p){
  return __half22float2(__builtin_bit_cast(__half2, p));
}

// Per-lane twiddles (forward sign e^{-i...}).
struct Twid { float2 w, w2, t[6]; };
__device__ __forceinline__ void mktw(Twid& T, int lane){
  T.w  = eix(-(2.0f * PI_F / 256.0f) * (float)lane);
  T.w2 = cmulf(T.w, T.w);
  #pragma unroll
  for (int st = 0; st < 6; ++st){
    const int d = 32 >> st;
    T.t[st] = eix(-(PI_F / (float)d) * (float)(lane & (d - 1)));  // W_{2d}^{lane mod d}
  }
}

// Hoisted-coefficient butterfly: out = v*A + p*B (complex). 8 VALU ops.
// PROVEN (round-8 bench passed with this form for both fwd and inv).
__device__ __forceinline__ float2 stage_ab(float2 v, float2 p, float Ax, float Ay, float Bx, float By){
  float2 o;
  o.x = v.x*Ax - v.y*Ay + p.x*Bx - p.y*By;
  o.y = v.x*Ay + v.y*Ax + p.x*By + p.y*Bx;
  return o;
}

// radix-4 head of forward DIF (per stream).
__device__ __forceinline__ void fwd_head(float2 v[4], const Twid& T){
  const float2 t0 = cadd(v[0], v[2]);
  const float2 b0 = cmulf(csub(v[0], v[2]), T.w);
  const float2 t1 = cadd(v[1], v[3]);
  const float2 w64 = make_float2(T.w.y, -T.w.x);           // w * (-i)
  const float2 b1 = cmulf(csub(v[1], v[3]), w64);
  v[0] = cadd(t0, t1);
  v[1] = cmulf(csub(t0, t1), T.w2);
  v[2] = cadd(b0, b1);
  v[3] = cmulf(csub(b0, b1), T.w2);
}
// radix-4 tail of inverse DIT (per stream).
__device__ __forceinline__ void inv_tail(float2 v[4], const Twid& T){
  const float2 uci = make_float2(T.w.y, T.w.x);             // conj(w)*i
  const float2 m1 = cmulc(v[1], T.w2);
  const float2 m3a = cmulc(v[3], T.w2);
  const float2 n0 = cadd(v[0], m1), n1 = csub(v[0], m1);
  const float2 n2 = cadd(v[2], m3a), n3 = csub(v[2], m3a);
  const float2 m2 = cmulc(n2, T.w);
  const float2 m3 = cmulf(n3, uci);
  v[0] = cadd(n0, m2); v[2] = csub(n0, m2);
  v[1] = cadd(n1, m3); v[3] = csub(n1, m3);
}

// Forward 256-pt DIF, hoisted coefficients. In natural, out scrambled (rev8).
__device__ __forceinline__ void fft256_fwd(float2 v[4], int lane, const Twid& T){
  fwd_head(v, T);
  #pragma unroll
  for (int st = 0; st < 6; ++st){
    const int d = 32 >> st;
    const float2 t = T.t[st];
    const bool hi = (lane & d) != 0;
    const float Ax = hi ? -t.x : 1.f, Ay = hi ? -t.y : 0.f;
    const float Bx = hi ?  t.x : 1.f, By = hi ?  t.y : 0.f;
    #pragma unroll
    for (int s = 0; s < 4; ++s){
      const float2 p = sx(v[s], d);
      v[s] = stage_ab(v[s], p, Ax, Ay, Bx, By);
    }
  }
}

// Dual forward (two independent rows), same hoisted coefficients shared.
__device__ __forceinline__ void fft256_fwd2(float2 a[4], float2 b[4], int lane, const Twid& T){
  fwd_head(a, T);
  fwd_head(b, T);
  #pragma unroll
  for (int st = 0; st < 6; ++st){
    const int d = 32 >> st;
    const float2 t = T.t[st];
    const bool hi = (lane & d) != 0;
    const float Ax = hi ? -t.x : 1.f, Ay = hi ? -t.y : 0.f;
    const float Bx = hi ?  t.x : 1.f, By = hi ?  t.y : 0.f;
    #pragma unroll
    for (int s = 0; s < 4; ++s){
      const float2 pa = sx(a[s], d);
      const float2 pb = sx(b[s], d);
      a[s] = stage_ab(a[s], pa, Ax, Ay, Bx, By);
      b[s] = stage_ab(b[s], pb, Ax, Ay, Bx, By);
    }
  }
}

// DUAL inverse 256-pt DIT (unnormalized), hoisted coefficients:
// lo: out = v + p*conj(t)  -> A=(1,0),      B=( t.x,-t.y)
// hi: out = p - v*conj(t)  -> A=(-t.x,t.y), B=(1,0)
// In scrambled (rev8), out natural.
__device__ __forceinline__ void fft256_inv2(float2 a[4], float2 b[4], int lane, const Twid& T){
  #pragma unroll
  for (int st = 0; st < 6; ++st){
    const int d = 1 << st;
    const float2 t = T.t[5 - st];
    const bool hi = (lane & d) != 0;
    const float Ax = hi ? -t.x : 1.f, Ay = hi ?  t.y : 0.f;
    const float Bx = hi ?  1.f : t.x, By = hi ?  0.f : -t.y;
    #pragma unroll
    for (int s = 0; s < 4; ++s){
      const float2 pa = sx(a[s], d);
      const float2 pb = sx(b[s], d);
      a[s] = stage_ab(a[s], pa, Ax, Ay, Bx, By);
      b[s] = stage_ab(b[s], pb, Ax, Ay, Bx, By);
    }
  }
  inv_tail(a, T);
  inv_tail(b, T);
}

// K0: scrambled Riesz scale table + zero row.
__global__ __launch_bounds__(256) void k0_prep(const float* __restrict__ km,
                                               float* __restrict__ sTabS,
                                               float* __restrict__ zrow){
  const int idx = blockIdx.x * 256 + threadIdx.x;
  const int q = idx >> 8, r = idx & 255;
  const int u = rev8(q), v = rev8(r);
  const float kv = km[u * 256 + v];
  float sp = fmaxf(kv, 0.f) + log1pf(expf(-fabsf(kv)));
  sp = fminf(fmaxf(sp, 1e-3f), 10.f);
  const float fu = (float)(u + 1), fv = (float)(v + 1);
  sTabS[idx] = sp / (sqrtf(fu * fu + fv * fv) + 1e-6f) * (1.0f / 65536.0f);
  if (blockIdx.x == 0){
    zrow[threadIdx.x] = 0.f;
    zrow[threadIdx.x + 256] = 0.f;
    if (threadIdx.x < 16) zrow[threadIdx.x + 512] = 0.f;
  }
}

// K1: forward row FFT. 2 rows per wave (dual-stream), 8 rows/block.
__global__ __launch_bounds__(256) void k1_row(const float* __restrict__ x, char* __restrict__ arena){
  const int grp = threadIdx.x >> 6, lane = threadIdx.x & 63;
  const int rs = blockIdx.x * 8 + grp * 2;
  Twid T; mktw(T, lane);
  const float* xr0 = x + (size_t)rs * 256;
  const float* xr1 = xr0 + 256;
  float2 a[4], b[4];
  #pragma unroll
  for (int s = 0; s < 4; ++s){
    a[s] = make_float2(xr0[lane + 64 * s], 0.f);
    b[s] = make_float2(xr1[lane + 64 * s], 0.f);
  }
  fft256_fwd2(a, b, lane, T);
  float2* S0 = (float2*)(arena + (size_t)rs * ROWB);
  float2* S1 = (float2*)(arena + (size_t)(rs + 1) * ROWB);
  #pragma unroll
  for (int s = 0; s < 4; ++s){ S0[lane + 64 * s] = a[s]; S1[lane + 64 * s] = b[s]; }
}

// K2: per (image, 8-col tile): col FFT, both Riesz filters, dual col IFFT; packed fp16 in place.
// Proven 9-pitch swizzled LDS; wave-private column slots -> in-place writeback.
__global__ __launch_bounds__(256) void k2_col(char* __restrict__ arena, const float* __restrict__ sTabS){
  __shared__ float2 lds[256 * 9];
  const int tid = threadIdx.x;
  const int b  = blockIdx.x >> 5;
  const int u0 = (blockIdx.x & 31) << 3;
  char* base = arena + (size_t)b * IMGB;

  #pragma unroll
  for (int k = 0; k < 8; ++k){
    const int idx = tid + (k << 8);
    const int r = idx >> 3, cc = idx & 7;
    lds[r * 9 + (cc ^ ((r >> 3) & 7))] = *(const float2*)(base + (size_t)r * ROWB + (size_t)(u0 + cc) * 8);
  }
  __syncthreads();

  const int wv = tid >> 6, lane = tid & 63;
  Twid T; mktw(T, lane);
  const int r6 = __brev(lane) >> 26;                 // rev6(lane)
  float fvv[4];
  fvv[0] = (float)(4 * r6 + 0 + 1);
  fvv[1] = (float)(4 * r6 + 2 + 1);
  fvv[2] = (float)(4 * r6 + 1 + 1);
  fvv[3] = (float)(4 * r6 + 3 + 1);
  const int swb = (lane >> 3) & 7;

  #pragma unroll
  for (int cp = 0; cp < 2; ++cp){
    const int c = wv * 2 + cp;
    const int q = u0 + c;
    const int swc = c ^ swb;
    float2 F[4];
    #pragma unroll
    for (int s = 0; s < 4; ++s) F[s] = lds[(lane + 64 * s) * 9 + swc];
    fft256_fwd(F, lane, T);
    float sc[4];
    #pragma unroll
    for (int s = 0; s < 4; ++s) sc[s] = sTabS[q * 256 + lane + 64 * s];
    const float fu = (float)(rev8((unsigned)q) + 1);
    float2 G1[4], G2[4];
    #pragma unroll
    for (int s = 0; s < 4; ++s){
      const float a1 = fvv[s] * sc[s];
      const float a2 = fu * sc[s];
      G1[s] = make_float2(a1 * F[s].y, -a1 * F[s].x);
      G2[s] = make_float2(a2 * F[s].y, -a2 * F[s].x);
    }
    fft256_inv2(G1, G2, lane, T);
    #pragma unroll
    for (int s = 0; s < 4; ++s)
      lds[(lane + 64 * s) * 9 + swc] =
          make_float2(__uint_as_float(packh2u(G1[s].x, G1[s].y)),
                      __uint_as_float(packh2u(G2[s].x, G2[s].y)));
  }
  __syncthreads();
  #pragma unroll
  for (int k = 0; k < 8; ++k){
    const int idx = tid + (k << 8);
    const int r = idx >> 3, cc = idx & 7;
    *(float2*)(base + (size_t)r * ROWB + (size_t)(u0 + cc) * 8) = lds[r * 9 + (cc ^ ((r >> 3) & 7))];
  }
}

// K3: dual row IFFT of packed U1/U2 + pointwise; writes A (f32) + PT (h2) in place over SPEC rows.
// Per-row sum -> rowsum (plain store; atomics were a measured 100 µs regression).
__global__ __launch_bounds__(256) void k3_rowinv(const float* __restrict__ x, char* __restrict__ arena,
    const float* __restrict__ ampw, const float* __restrict__ ampb,
    float* __restrict__ rowsum){
  const int grp = threadIdx.x >> 6, lane = threadIdx.x & 63;
  const int rs = blockIdx.x * 4 + grp;
  Twid T; mktw(T, lane);
  char* rowb = arena + (size_t)rs * ROWB;
  float2 g1[4], g2[4];
  #pragma unroll
  for (int s = 0; s < 4; ++s){
    const float2 pk = *(const float2*)(rowb + (size_t)(lane + 64 * s) * 8);
    g1[s] = unpackh2(pk.x); g2[s] = unpackh2(pk.y);
  }
  fft256_inv2(g1, g2, lane, T);
  const float aw = *ampw, ab = *ampb;
  const float* xr = x + (size_t)rs * 256;
  float* Arow = (float*)(rowb + 16);
  unsigned* Prow = (unsigned*)(rowb + 1072);
  float sum = 0.f;
  #pragma unroll
  for (int s = 0; s < 4; ++s){
    const int j = lane + 64 * s;
    const float xv = xr[j];
    const float R1 = sqrtf(fmaf(g1[s].x, g1[s].x, g1[s].y * g1[s].y)) + 1e-6f;
    const float R2 = sqrtf(fmaf(g2[s].x, g2[s].x, g2[s].y * g2[s].y)) + 1e-6f;
    const float rr = fmaf(R1, R1, R2 * R2);
    const float A = sqrtf(fmaxf(fmaf(xv, xv, rr), 0.f) + 1e-6f);
    const float P  = fast_atan2pos(sqrtf(rr) + 1e-6f, xv + 1e-6f);
    const float Th = fast_atan2pos(R2, R1 + 1e-6f);
    const float Ab = A + fmaxf(fmaf(aw, A, ab), 0.f);
    Arow[j] = Ab;
    Prow[j] = packh2u(P, Th);
    sum += Ab;
  }
  #pragma unroll
  for (int off = 32; off; off >>= 1) sum += __shfl_down(sum, off);
  if (lane == 0) rowsum[rs] = sum;
}

// KPAD: zero column halos of A and PT segments.
__global__ __launch_bounds__(256) void kpad(char* __restrict__ arena){
  char* row = arena + (size_t)blockIdx.x * IMGB + (size_t)threadIdx.x * ROWB;
  const float4 z = make_float4(0.f, 0.f, 0.f, 0.f);
  *(float4*)(row)         = z;   // A cols -4..-1
  *(float4*)(row + 1040)  = z;   // A cols 256..259
  *(float4*)(row + 1056)  = z;   // PT cols -4..-1
  *(float4*)(row + 2096)  = z;   // PT cols 256..259
}

// K4: per-image gate from 256 row sums.
__global__ __launch_bounds__(256) void k4_gw(const float* __restrict__ rowsum,
    const float* __restrict__ fc1w, const float* __restrict__ fc1b,
    const float* __restrict__ fc2w, const float* __restrict__ fc2b,
    float* __restrict__ gw){
  __shared__ float red[256];
  const int tid = threadIdx.x;
  red[tid] = rowsum[blockIdx.x * 256 + tid];
  __syncthreads();
  #pragma unroll
  for (int off = 128; off; off >>= 1){
    if (tid < off) red[tid] += red[tid + off];
    __syncthreads();
  }
  if (tid == 0){
    const float gf = red[0] * (1.0f / 65536.0f);
    float acc = fc2b[0];
    #pragma unroll
    for (int k = 0; k < 16; ++k)
      acc += fc2w[k] * fmaxf(gf * fc1w[k] + fc1b[k], 0.f);
    gw[blockIdx.x] = frcp(1.f + __expf(-acc));
  }
}

// K5: register-blocked 4x4/thread convs + fusion; row-halo via zero-row pointer.
__global__ __launch_bounds__(256) void k5_fuse(
    const char* __restrict__ arena, const float* __restrict__ zrowf,
    const float* __restrict__ gwp,
    const float* __restrict__ theta_w, const float* __restrict__ theta_b,
    const float* __restrict__ phase_w, const float* __restrict__ phase_b,
    const float* __restrict__ phase_gamma, const float* __restrict__ phase_beta,
    const float* __restrict__ phase_mean, const float* __restrict__ phase_var,
    const float* __restrict__ ms_w1, const float* __restrict__ ms_b1,
    const float* __restrict__ ms_w2, const float* __restrict__ ms_b2,
    const float* __restrict__ ms_w3, const float* __restrict__ ms_b3,
    const float* __restrict__ fin_w, const float* __restrict__ fin_b,
    const float* __restrict__ fin_gamma, const float* __restrict__ fin_beta,
    const float* __restrict__ fin_mean, const float* __restrict__ fin_var,
    float* __restrict__ out){
  const int z = blockIdx.z;
  const int tx = threadIdx.x & 15, ty = threadIdx.x >> 4;
  const int j0 = (blockIdx.x << 6) + (tx << 2);
  const int i0 = (blockIdx.y << 6) + (ty << 2);
  const char* img = arena + (size_t)z * IMGB;

  float tw9[9], pw9[9], w1[9], w2[9], w3[9];
  #pragma unroll
  for (int k = 0; k < 9; ++k){
    tw9[k] = theta_w[k]; pw9[k] = phase_w[k];
    w1[k] = ms_w1[k]; w2[k] = ms_w2[k]; w3[k] = ms_w3[k];
  }
  const float b1s = ms_b1[0], b2s = ms_b2[0], b3s = ms_b3[0];
  const float tbs = theta_b[0], pbs = phase_b[0];

  float4 m1[4], m2[4], m3[4], at[4], ap[4], Ac[4], Tc[4];
  #pragma unroll
  for (int oi = 0; oi < 4; ++oi){
    m1[oi] = make_float4(b1s, b1s, b1s, b1s);
    m2[oi] = make_float4(b2s, b2s, b2s, b2s);
    m3[oi] = make_float4(b3s, b3s, b3s, b3s);
    at[oi] = make_float4(tbs, tbs, tbs, tbs);
    ap[oi] = make_float4(pbs, pbs, pbs, pbs);
  }

  // ---- A-plane (rows i0-3 .. i0+6, cols j0-4 .. j0+7) ----
  #pragma unroll
  for (int lr = 0; lr < 10; ++lr){
    const int ar = i0 - 3 + lr;
    const float* rowA = ((unsigned)ar < 256u) ? (const float*)(img + (size_t)ar * ROWB) : zrowf;
    const float4 va = *(const float4*)(rowA + j0);
    const float4 vb = *(const float4*)(rowA + j0 + 4);
    const float4 vc = *(const float4*)(rowA + j0 + 8);
    const float a[12] = {va.x, va.y, va.z, va.w, vb.x, vb.y, vb.z, vb.w, vc.x, vc.y, vc.z, vc.w};
    #pragma unroll
    for (int oi = 0; oi < 4; ++oi){
      const int dd = lr - 3 - oi;
      if (dd >= -1 && dd <= 1){
        const int wr = (dd + 1) * 3;
        #pragma unroll
        for (int dx = -1; dx <= 1; ++dx){
          const float w = w1[wr + dx + 1];
          m1[oi].x += w * a[4 + 0 + dx]; m1[oi].y += w * a[4 + 1 + dx];
          m1[oi].z += w * a[4 + 2 + dx]; m1[oi].w += w * a[4 + 3 + dx];
        }
      }
      if (dd == -2 || dd == 0 || dd == 2){
        const int wr = (dd / 2 + 1) * 3;
        #pragma unroll
        for (int dx = -1; dx <= 1; ++dx){
          const float w = w2[wr + dx + 1];
          m2[oi].x += w * a[4 + 0 + 2 * dx]; m2[oi].y += w * a[4 + 1 + 2 * dx];
          m2[oi].z += w * a[4 + 2 + 2 * dx]; m2[oi].w += w * a[4 + 3 + 2 * dx];
        }
      }
      if (dd == -3 || dd == 0 || dd == 3){
        const int wr = (dd / 3 + 1) * 3;
        #pragma unroll
        for (int dx = -1; dx <= 1; ++dx){
          const float w = w3[wr + dx + 1];
          m3[oi].x += w * a[4 + 0 + 3 * dx]; m3[oi].y += w * a[4 + 1 + 3 * dx];
          m3[oi].z += w * a[4 + 2 + 3 * dx]; m3[oi].w += w * a[4 + 3 + 3 * dx];
        }
      }
      if (dd == 0) Ac[oi] = make_float4(a[4], a[5], a[6], a[7]);
    }
  }

  // ---- PT-plane (rows i0-1 .. i0+4) ----
  #pragma unroll
  for (int lr = 0; lr < 6; ++lr){
    const int ar = i0 - 1 + lr;
    const unsigned* rowP = ((unsigned)ar < 256u) ? (const unsigned*)(img + (size_t)ar * ROWB + 1056)
                                                 : (const unsigned*)zrowf;
    const uint4 ua = *(const uint4*)(rowP + j0);
    const uint4 ub = *(const uint4*)(rowP + j0 + 4);
    const uint4 uc = *(const uint4*)(rowP + j0 + 8);
    const unsigned uu[12] = {ua.x, ua.y, ua.z, ua.w, ub.x, ub.y, ub.z, ub.w, uc.x, uc.y, uc.z, uc.w};
    float p[12], t[12];
    #pragma unroll
    for (int k = 0; k < 12; ++k){
      const float2 pt = unpackh2(__builtin_bit_cast(float, uu[k]));
      p[k] = pt.x; t[k] = pt.y;
    }
    #pragma unroll
    for (int oi = 0; oi < 4; ++oi){
      const int dd = lr - 1 - oi;
      if (dd >= -1 && dd <= 1){
        const int wr = (dd + 1) * 3;
        #pragma unroll
        for (int dx = -1; dx <= 1; ++dx){
          const float wp = pw9[wr + dx + 1], wt = tw9[wr + dx + 1];
          ap[oi].x += wp * p[4 + 0 + dx]; ap[oi].y += wp * p[4 + 1 + dx];
          ap[oi].z += wp * p[4 + 2 + dx]; ap[oi].w += wp * p[4 + 3 + dx];
          at[oi].x += wt * t[4 + 0 + dx]; at[oi].y += wt * t[4 + 1 + dx];
          at[oi].z += wt * t[4 + 2 + dx]; at[oi].w += wt * t[4 + 3 + dx];
        }
      }
      if (dd == 0) Tc[oi] = make_float4(t[4], t[5], t[6], t[7]);
    }
  }

  // ---- epilogue ----
  const float gwb = gwp[z];
  const float inv_p = phase_gamma[0] * rsqrtf(phase_var[0] + 1e-5f);
  const float pmean = phase_mean[0], pbeta = phase_beta[0];
  const float f0 = fin_w[0], f1 = fin_w[1], f2 = fin_w[2];
  const float f3 = fin_w[3], f4 = fin_w[4], f5 = fin_w[5];
  const float fb = fin_b[0];
  const float inv_f = fin_gamma[0] * rsqrtf(fin_var[0] + 1e-5f);
  const float fmean = fin_mean[0], fbeta = fin_beta[0];

  #pragma unroll
  for (int oi = 0; oi < 4; ++oi){
    const float mm1[4] = {m1[oi].x, m1[oi].y, m1[oi].z, m1[oi].w};
    const float mm2[4] = {m2[oi].x, m2[oi].y, m2[oi].z, m2[oi].w};
    const float mm3[4] = {m3[oi].x, m3[oi].y, m3[oi].z, m3[oi].w};
    const float tt[4]  = {at[oi].x, at[oi].y, at[oi].z, at[oi].w};
    const float pp[4]  = {ap[oi].x, ap[oi].y, ap[oi].z, ap[oi].w};
    const float ac[4]  = {Ac[oi].x, Ac[oi].y, Ac[oi].z, Ac[oi].w};
    const float tc[4]  = {Tc[oi].x, Tc[oi].y, Tc[oi].z, Tc[oi].w};
    float o4[4];
    #pragma unroll
    for (int oj = 0; oj < 4; ++oj){
      const float Gt = tc[oj] * frcp(1.f + __expf(-tt[oj]));
      const float Pp = fmaxf((pp[oj] - pmean) * inv_p + pbeta, 0.f);
      const float pre = f0 * ac[oj] + f1 * Pp + f2 * Gt
                      + gwb * (f3 * mm1[oj] + f4 * mm2[oj] + f5 * mm3[oj]) + fb;
      float o = (pre - fmean) * inv_f + fbeta;
      o4[oj] = fminf(fmaxf(o, 0.f), 1.f);
    }
    *(float4*)(out + ((size_t)(z * 256 + i0 + oi) << 8) + j0) = make_float4(o4[0], o4[1], o4[2], o4[3]);
  }
}

extern "C" void kernel_launch(void* const* d_in, const int* in_sizes, int n_in,
                              void* d_out, int out_size, void* d_ws, size_t ws_size,
                              hipStream_t stream){
  const float* x  = (const float*)d_in[0];
  const float* km = (const float*)d_in[1];

  // layout: [arena: imgsPer*IMGB] [zrow 2112] [sTabS 262144] [gw 1024] [rowsum rowsPer*4]
  int N = 1;
  while (N < 64){
    const size_t need = (size_t)(256 / N) * IMGB + 2112ull + 262144ull + 1024ull
                      + (size_t)(256 / N) * 1024ull;
    if (need <= ws_size) break;
    N <<= 1;
  }
  const int imgsPer = 256 / N;
  const int rowsPer = imgsPer * 256;

  char*  ws     = (char*)d_ws;
  char*  arena  = ws;
  float* zrow   = (float*)(ws + (size_t)imgsPer * IMGB);
  float* sTabS  = (float*)(ws + (size_t)imgsPer * IMGB + 2112ull);
  float* gwbuf  = (float*)(ws + (size_t)imgsPer * IMGB + 2112ull + 262144ull);
  float* rowsum = (float*)(ws + (size_t)imgsPer * IMGB + 2112ull + 262144ull + 1024ull);

  k0_prep<<<256, 256, 0, stream>>>(km, sTabS, zrow);

  for (int s = 0; s < N; ++s){
    const float* xs = x + (size_t)s * rowsPer * 256;
    float* outs = (float*)d_out + (size_t)s * rowsPer * 256;

    k1_row<<<rowsPer / 8, 256, 0, stream>>>(xs, arena);
    k2_col<<<imgsPer * 32, 256, 0, stream>>>(arena, sTabS);
    k3_rowinv<<<rowsPer / 4, 256, 0, stream>>>(xs, arena,
        (const float*)d_in[10], (const float*)d_in[11], rowsum);
    kpad<<<imgsPer, 256, 0, stream>>>(arena);
    k4_gw<<<imgsPer, 256, 0, stream>>>(rowsum,
        (const float*)d_in[18], (const float*)d_in[19],
        (const float*)d_in[20], (const float*)d_in[21], gwbuf);
    k5_fuse<<<dim3(4, 4, imgsPer), 256, 0, stream>>>(
        arena, zrow, gwbuf,
        (const float*)d_in[2],  (const float*)d_in[3],
        (const float*)d_in[4],  (const float*)d_in[5],
        (const float*)d_in[6],  (const float*)d_in[7],
        (const float*)d_in[8],  (const float*)d_in[9],
        (const float*)d_in[12], (const float*)d_in[13],
        (const float*)d_in[14], (const float*)d_in[15],
        (const float*)d_in[16], (const float*)d_in[17],
        (const float*)d_in[22], (const float*)d_in[23],
        (const float*)d_in[24], (const float*)d_in[25],
        (const float*)d_in[26], (const float*)d_in[27],
        outs);
  }
}

// Round 14
// 367.900 us; speedup vs baseline: 1.0778x; 1.0277x over previous
//
#include <hip/hip_runtime.h>
#include <hip/hip_fp16.h>
#include <math.h>

#define PI_F 3.14159265358979323846f
#define ROWB 2112ull            // bytes per arena row
#define IMGB (ROWB * 256ull)    // 540672 bytes per image

__device__ __forceinline__ unsigned rev8(unsigned v){ return __brev(v) >> 24; }

__device__ __forceinline__ float2 cmulf(float2 a, float2 b){ return make_float2(a.x*b.x - a.y*b.y, a.x*b.y + a.y*b.x); }
__device__ __forceinline__ float2 cmulc(float2 a, float2 b){ return make_float2(a.x*b.x + a.y*b.y, a.y*b.x - a.x*b.y); } // a*conj(b)
__device__ __forceinline__ float2 cadd (float2 a, float2 b){ return make_float2(a.x+b.x, a.y+b.y); }
__device__ __forceinline__ float2 csub (float2 a, float2 b){ return make_float2(a.x-b.x, a.y-b.y); }
__device__ __forceinline__ float2 eix(float a){ float s, c; __sincosf(a, &s, &c); return make_float2(c, s); }
__device__ __forceinline__ float2 sx(float2 v, int d){ return make_float2(__shfl_xor(v.x, d), __shfl_xor(v.y, d)); }

__device__ __forceinline__ float frcp(float x){ float r; asm("v_rcp_f32 %0, %1" : "=v"(r) : "v"(x)); return r; }

// atan2(y,x) for y > 0 (result in (0, pi)). Deg-11 odd minimax, err ~2e-6 rad.
__device__ __forceinline__ float fast_atan2pos(float y, float x){
  const float ax = fabsf(x);
  const float mn = fminf(ax, y), mx = fmaxf(ax, y);
  const float t  = mn * frcp(mx);
  const float z  = t * t;
  float p = -0.01172120f;
  p = fmaf(p, z,  0.05265332f);
  p = fmaf(p, z, -0.11643287f);
  p = fmaf(p, z,  0.19354346f);
  p = fmaf(p, z, -0.33262347f);
  p = fmaf(p, z,  0.99997726f);
  p = p * t;
  p = (y > ax) ? (1.57079632679f - p) : p;
  p = (x < 0.f) ? (3.14159265359f - p) : p;
  return p;
}

__device__ __forceinline__ unsigned packh2u(float a, float b){
  return __builtin_bit_cast(unsigned, __floats2half2_rn(a, b));
}
__device__ __forceinline__ float2 unpackh2(float p){
  return __half22float2(__builtin_bit_cast(__half2, p));
}

// Per-lane twiddles (forward sign e^{-i...}).
struct Twid { float2 w, w2, t[6]; };
__device__ __forceinline__ void mktw(Twid& T, int lane){
  T.w  = eix(-(2.0f * PI_F / 256.0f) * (float)lane);
  T.w2 = cmulf(T.w, T.w);
  #pragma unroll
  for (int st = 0; st < 6; ++st){
    const int d = 32 >> st;
    T.t[st] = eix(-(PI_F / (float)d) * (float)(lane & (d - 1)));  // W_{2d}^{lane mod d}
  }
}

// radix-4 head of forward DIF (per stream).
__device__ __forceinline__ void fwd_head(float2 v[4], const Twid& T){
  const float2 t0 = cadd(v[0], v[2]);
  const float2 b0 = cmulf(csub(v[0], v[2]), T.w);
  const float2 t1 = cadd(v[1], v[3]);
  const float2 w64 = make_float2(T.w.y, -T.w.x);           // w * (-i)
  const float2 b1 = cmulf(csub(v[1], v[3]), w64);
  v[0] = cadd(t0, t1);
  v[1] = cmulf(csub(t0, t1), T.w2);
  v[2] = cadd(b0, b1);
  v[3] = cmulf(csub(b0, b1), T.w2);
}
// radix-4 tail of inverse DIT (per stream).
__device__ __forceinline__ void inv_tail(float2 v[4], const Twid& T){
  const float2 uci = make_float2(T.w.y, T.w.x);             // conj(w)*i
  const float2 m1 = cmulc(v[1], T.w2);
  const float2 m3a = cmulc(v[3], T.w2);
  const float2 n0 = cadd(v[0], m1), n1 = csub(v[0], m1);
  const float2 n2 = cadd(v[2], m3a), n3 = csub(v[2], m3a);
  const float2 m2 = cmulc(n2, T.w);
  const float2 m3 = cmulf(n3, uci);
  v[0] = cadd(n0, m2); v[2] = csub(n0, m2);
  v[1] = cadd(n1, m3); v[3] = csub(n1, m3);
}

// ---------- SELECT-FORM FFTs (r12-proven; used by k2 where VGPR is tight) ----------
__device__ __forceinline__ void fft256_fwd_sel(float2 v[4], int lane, const Twid& T){
  fwd_head(v, T);
  #pragma unroll
  for (int st = 0; st < 6; ++st){
    const int d = 32 >> st;
    const float2 tw = T.t[st];
    const bool hi = (lane & d) != 0;
    #pragma unroll
    for (int s = 0; s < 4; ++s){
      const float2 p  = sx(v[s], d);
      const float2 bo = cmulf(csub(p, v[s]), tw);
      const float2 lo = cadd(v[s], p);
      v[s] = hi ? bo : lo;
    }
  }
}
__device__ __forceinline__ void fft256_inv2_sel(float2 a[4], float2 b[4], int lane, const Twid& T){
  #pragma unroll
  for (int st = 0; st < 6; ++st){
    const int d = 1 << st;
    const float2 tw = T.t[5 - st];
    const bool hi = (lane & d) != 0;
    #pragma unroll
    for (int s = 0; s < 4; ++s){
      const float2 pa = sx(a[s], d);
      const float2 pb = sx(b[s], d);
      const float2 ma = cmulc(hi ? a[s] : pa, tw);
      const float2 mb = cmulc(hi ? b[s] : pb, tw);
      a[s] = hi ? csub(pa, ma) : cadd(a[s], ma);
      b[s] = hi ? csub(pb, mb) : cadd(b[s], mb);
    }
  }
  inv_tail(a, T);
  inv_tail(b, T);
}

// ---------- HOISTED-FORM FFTs (r13-proven win in high-occupancy kernels k1/k3) ----------
__device__ __forceinline__ float2 stage_ab(float2 v, float2 p, float Ax, float Ay, float Bx, float By){
  float2 o;
  o.x = v.x*Ax - v.y*Ay + p.x*Bx - p.y*By;
  o.y = v.x*Ay + v.y*Ax + p.x*By + p.y*Bx;
  return o;
}
__device__ __forceinline__ void fft256_fwd2(float2 a[4], float2 b[4], int lane, const Twid& T){
  fwd_head(a, T);
  fwd_head(b, T);
  #pragma unroll
  for (int st = 0; st < 6; ++st){
    const int d = 32 >> st;
    const float2 t = T.t[st];
    const bool hi = (lane & d) != 0;
    const float Ax = hi ? -t.x : 1.f, Ay = hi ? -t.y : 0.f;
    const float Bx = hi ?  t.x : 1.f, By = hi ?  t.y : 0.f;
    #pragma unroll
    for (int s = 0; s < 4; ++s){
      const float2 pa = sx(a[s], d);
      const float2 pb = sx(b[s], d);
      a[s] = stage_ab(a[s], pa, Ax, Ay, Bx, By);
      b[s] = stage_ab(b[s], pb, Ax, Ay, Bx, By);
    }
  }
}
// lo: out = v + p*conj(t) -> A=(1,0), B=(t.x,-t.y); hi: out = p - v*conj(t) -> A=(-t.x,t.y), B=(1,0)
__device__ __forceinline__ void fft256_inv2(float2 a[4], float2 b[4], int lane, const Twid& T){
  #pragma unroll
  for (int st = 0; st < 6; ++st){
    const int d = 1 << st;
    const float2 t = T.t[5 - st];
    const bool hi = (lane & d) != 0;
    const float Ax = hi ? -t.x : 1.f, Ay = hi ?  t.y : 0.f;
    const float Bx = hi ?  1.f : t.x, By = hi ?  0.f : -t.y;
    #pragma unroll
    for (int s = 0; s < 4; ++s){
      const float2 pa = sx(a[s], d);
      const float2 pb = sx(b[s], d);
      a[s] = stage_ab(a[s], pa, Ax, Ay, Bx, By);
      b[s] = stage_ab(b[s], pb, Ax, Ay, Bx, By);
    }
  }
  inv_tail(a, T);
  inv_tail(b, T);
}

// K0: scrambled Riesz scale table + zero row.
__global__ __launch_bounds__(256) void k0_prep(const float* __restrict__ km,
                                               float* __restrict__ sTabS,
                                               float* __restrict__ zrow){
  const int idx = blockIdx.x * 256 + threadIdx.x;
  const int q = idx >> 8, r = idx & 255;
  const int u = rev8(q), v = rev8(r);
  const float kv = km[u * 256 + v];
  float sp = fmaxf(kv, 0.f) + log1pf(expf(-fabsf(kv)));
  sp = fminf(fmaxf(sp, 1e-3f), 10.f);
  const float fu = (float)(u + 1), fv = (float)(v + 1);
  sTabS[idx] = sp / (sqrtf(fu * fu + fv * fv) + 1e-6f) * (1.0f / 65536.0f);
  if (blockIdx.x == 0){
    zrow[threadIdx.x] = 0.f;
    zrow[threadIdx.x + 256] = 0.f;
    if (threadIdx.x < 16) zrow[threadIdx.x + 512] = 0.f;
  }
}

// K1: forward row FFT. 2 rows per wave (hoisted dual), 8 rows/block.
__global__ __launch_bounds__(256) void k1_row(const float* __restrict__ x, char* __restrict__ arena){
  const int grp = threadIdx.x >> 6, lane = threadIdx.x & 63;
  const int rs = blockIdx.x * 8 + grp * 2;
  Twid T; mktw(T, lane);
  const float* xr0 = x + (size_t)rs * 256;
  const float* xr1 = xr0 + 256;
  float2 a[4], b[4];
  #pragma unroll
  for (int s = 0; s < 4; ++s){
    a[s] = make_float2(xr0[lane + 64 * s], 0.f);
    b[s] = make_float2(xr1[lane + 64 * s], 0.f);
  }
  fft256_fwd2(a, b, lane, T);
  float2* S0 = (float2*)(arena + (size_t)rs * ROWB);
  float2* S1 = (float2*)(arena + (size_t)(rs + 1) * ROWB);
  #pragma unroll
  for (int s = 0; s < 4; ++s){ S0[lane + 64 * s] = a[s]; S1[lane + 64 * s] = b[s]; }
}

// K2: per (image, 8-col tile): col FFT, both Riesz filters, dual col IFFT; packed fp16 in place.
// 512 threads = 8 waves, ONE column per wave (halved serial chain, doubled TLP).
// Select-form FFTs (r12-proven VGPR profile). Proven 9-pitch swizzled LDS; wave-private
// column slots -> in-place writeback.
__global__ __launch_bounds__(512) void k2_col(char* __restrict__ arena, const float* __restrict__ sTabS){
  __shared__ float2 lds[256 * 9];
  const int tid = threadIdx.x;
  const int b  = blockIdx.x >> 5;
  const int u0 = (blockIdx.x & 31) << 3;
  char* base = arena + (size_t)b * IMGB;

  #pragma unroll
  for (int k = 0; k < 4; ++k){
    const int idx = tid + (k << 9);
    const int r = idx >> 3, cc = idx & 7;
    lds[r * 9 + (cc ^ ((r >> 3) & 7))] = *(const float2*)(base + (size_t)r * ROWB + (size_t)(u0 + cc) * 8);
  }
  __syncthreads();

  const int wv = tid >> 6, lane = tid & 63;
  Twid T; mktw(T, lane);
  const int r6 = __brev(lane) >> 26;                 // rev6(lane)
  float fvv[4];
  fvv[0] = (float)(4 * r6 + 0 + 1);
  fvv[1] = (float)(4 * r6 + 2 + 1);
  fvv[2] = (float)(4 * r6 + 1 + 1);
  fvv[3] = (float)(4 * r6 + 3 + 1);
  const int swb = (lane >> 3) & 7;

  {
    const int c = wv;                                // one column per wave
    const int q = u0 + c;
    const int swc = c ^ swb;
    float2 F[4];
    #pragma unroll
    for (int s = 0; s < 4; ++s) F[s] = lds[(lane + 64 * s) * 9 + swc];
    fft256_fwd_sel(F, lane, T);
    float sc[4];
    #pragma unroll
    for (int s = 0; s < 4; ++s) sc[s] = sTabS[q * 256 + lane + 64 * s];
    const float fu = (float)(rev8((unsigned)q) + 1);
    float2 G1[4], G2[4];
    #pragma unroll
    for (int s = 0; s < 4; ++s){
      const float a1 = fvv[s] * sc[s];
      const float a2 = fu * sc[s];
      G1[s] = make_float2(a1 * F[s].y, -a1 * F[s].x);
      G2[s] = make_float2(a2 * F[s].y, -a2 * F[s].x);
    }
    fft256_inv2_sel(G1, G2, lane, T);
    #pragma unroll
    for (int s = 0; s < 4; ++s)
      lds[(lane + 64 * s) * 9 + swc] =
          make_float2(__uint_as_float(packh2u(G1[s].x, G1[s].y)),
                      __uint_as_float(packh2u(G2[s].x, G2[s].y)));
  }
  __syncthreads();
  #pragma unroll
  for (int k = 0; k < 4; ++k){
    const int idx = tid + (k << 9);
    const int r = idx >> 3, cc = idx & 7;
    *(float2*)(base + (size_t)r * ROWB + (size_t)(u0 + cc) * 8) = lds[r * 9 + (cc ^ ((r >> 3) & 7))];
  }
}

// K3: dual row IFFT (hoisted, r13-proven) of packed U1/U2 + pointwise; in-place over SPEC rows.
// Per-row sum -> rowsum (plain store; atomics were a measured 100 µs regression).
__global__ __launch_bounds__(256) void k3_rowinv(const float* __restrict__ x, char* __restrict__ arena,
    const float* __restrict__ ampw, const float* __restrict__ ampb,
    float* __restrict__ rowsum){
  const int grp = threadIdx.x >> 6, lane = threadIdx.x & 63;
  const int rs = blockIdx.x * 4 + grp;
  Twid T; mktw(T, lane);
  char* rowb = arena + (size_t)rs * ROWB;
  float2 g1[4], g2[4];
  #pragma unroll
  for (int s = 0; s < 4; ++s){
    const float2 pk = *(const float2*)(rowb + (size_t)(lane + 64 * s) * 8);
    g1[s] = unpackh2(pk.x); g2[s] = unpackh2(pk.y);
  }
  fft256_inv2(g1, g2, lane, T);
  const float aw = *ampw, ab = *ampb;
  const float* xr = x + (size_t)rs * 256;
  float* Arow = (float*)(rowb + 16);
  unsigned* Prow = (unsigned*)(rowb + 1072);
  float sum = 0.f;
  #pragma unroll
  for (int s = 0; s < 4; ++s){
    const int j = lane + 64 * s;
    const float xv = xr[j];
    const float R1 = sqrtf(fmaf(g1[s].x, g1[s].x, g1[s].y * g1[s].y)) + 1e-6f;
    const float R2 = sqrtf(fmaf(g2[s].x, g2[s].x, g2[s].y * g2[s].y)) + 1e-6f;
    const float rr = fmaf(R1, R1, R2 * R2);
    const float A = sqrtf(fmaxf(fmaf(xv, xv, rr), 0.f) + 1e-6f);
    const float P  = fast_atan2pos(sqrtf(rr) + 1e-6f, xv + 1e-6f);
    const float Th = fast_atan2pos(R2, R1 + 1e-6f);
    const float Ab = A + fmaxf(fmaf(aw, A, ab), 0.f);
    Arow[j] = Ab;
    Prow[j] = packh2u(P, Th);
    sum += Ab;
  }
  #pragma unroll
  for (int off = 32; off; off >>= 1) sum += __shfl_down(sum, off);
  if (lane == 0) rowsum[rs] = sum;
}

// KPAD: zero column halos of A and PT segments.
__global__ __launch_bounds__(256) void kpad(char* __restrict__ arena){
  char* row = arena + (size_t)blockIdx.x * IMGB + (size_t)threadIdx.x * ROWB;
  const float4 z = make_float4(0.f, 0.f, 0.f, 0.f);
  *(float4*)(row)         = z;   // A cols -4..-1
  *(float4*)(row + 1040)  = z;   // A cols 256..259
  *(float4*)(row + 1056)  = z;   // PT cols -4..-1
  *(float4*)(row + 2096)  = z;   // PT cols 256..259
}

// K4: per-image gate from 256 row sums.
__global__ __launch_bounds__(256) void k4_gw(const float* __restrict__ rowsum,
    const float* __restrict__ fc1w, const float* __restrict__ fc1b,
    const float* __restrict__ fc2w, const float* __restrict__ fc2b,
    float* __restrict__ gw){
  __shared__ float red[256];
  const int tid = threadIdx.x;
  red[tid] = rowsum[blockIdx.x * 256 + tid];
  __syncthreads();
  #pragma unroll
  for (int off = 128; off; off >>= 1){
    if (tid < off) red[tid] += red[tid + off];
    __syncthreads();
  }
  if (tid == 0){
    const float gf = red[0] * (1.0f / 65536.0f);
    float acc = fc2b[0];
    #pragma unroll
    for (int k = 0; k < 16; ++k)
      acc += fc2w[k] * fmaxf(gf * fc1w[k] + fc1b[k], 0.f);
    gw[blockIdx.x] = frcp(1.f + __expf(-acc));
  }
}

// K5: register-blocked 4x4/thread convs + fusion; row-halo via zero-row pointer.
__global__ __launch_bounds__(256) void k5_fuse(
    const char* __restrict__ arena, const float* __restrict__ zrowf,
    const float* __restrict__ gwp,
    const float* __restrict__ theta_w, const float* __restrict__ theta_b,
    const float* __restrict__ phase_w, const float* __restrict__ phase_b,
    const float* __restrict__ phase_gamma, const float* __restrict__ phase_beta,
    const float* __restrict__ phase_mean, const float* __restrict__ phase_var,
    const float* __restrict__ ms_w1, const float* __restrict__ ms_b1,
    const float* __restrict__ ms_w2, const float* __restrict__ ms_b2,
    const float* __restrict__ ms_w3, const float* __restrict__ ms_b3,
    const float* __restrict__ fin_w, const float* __restrict__ fin_b,
    const float* __restrict__ fin_gamma, const float* __restrict__ fin_beta,
    const float* __restrict__ fin_mean, const float* __restrict__ fin_var,
    float* __restrict__ out){
  const int z = blockIdx.z;
  const int tx = threadIdx.x & 15, ty = threadIdx.x >> 4;
  const int j0 = (blockIdx.x << 6) + (tx << 2);
  const int i0 = (blockIdx.y << 6) + (ty << 2);
  const char* img = arena + (size_t)z * IMGB;

  float tw9[9], pw9[9], w1[9], w2[9], w3[9];
  #pragma unroll
  for (int k = 0; k < 9; ++k){
    tw9[k] = theta_w[k]; pw9[k] = phase_w[k];
    w1[k] = ms_w1[k]; w2[k] = ms_w2[k]; w3[k] = ms_w3[k];
  }
  const float b1s = ms_b1[0], b2s = ms_b2[0], b3s = ms_b3[0];
  const float tbs = theta_b[0], pbs = phase_b[0];

  float4 m1[4], m2[4], m3[4], at[4], ap[4], Ac[4], Tc[4];
  #pragma unroll
  for (int oi = 0; oi < 4; ++oi){
    m1[oi] = make_float4(b1s, b1s, b1s, b1s);
    m2[oi] = make_float4(b2s, b2s, b2s, b2s);
    m3[oi] = make_float4(b3s, b3s, b3s, b3s);
    at[oi] = make_float4(tbs, tbs, tbs, tbs);
    ap[oi] = make_float4(pbs, pbs, pbs, pbs);
  }

  // ---- A-plane (rows i0-3 .. i0+6, cols j0-4 .. j0+7) ----
  #pragma unroll
  for (int lr = 0; lr < 10; ++lr){
    const int ar = i0 - 3 + lr;
    const float* rowA = ((unsigned)ar < 256u) ? (const float*)(img + (size_t)ar * ROWB) : zrowf;
    const float4 va = *(const float4*)(rowA + j0);
    const float4 vb = *(const float4*)(rowA + j0 + 4);
    const float4 vc = *(const float4*)(rowA + j0 + 8);
    const float a[12] = {va.x, va.y, va.z, va.w, vb.x, vb.y, vb.z, vb.w, vc.x, vc.y, vc.z, vc.w};
    #pragma unroll
    for (int oi = 0; oi < 4; ++oi){
      const int dd = lr - 3 - oi;
      if (dd >= -1 && dd <= 1){
        const int wr = (dd + 1) * 3;
        #pragma unroll
        for (int dx = -1; dx <= 1; ++dx){
          const float w = w1[wr + dx + 1];
          m1[oi].x += w * a[4 + 0 + dx]; m1[oi].y += w * a[4 + 1 + dx];
          m1[oi].z += w * a[4 + 2 + dx]; m1[oi].w += w * a[4 + 3 + dx];
        }
      }
      if (dd == -2 || dd == 0 || dd == 2){
        const int wr = (dd / 2 + 1) * 3;
        #pragma unroll
        for (int dx = -1; dx <= 1; ++dx){
          const float w = w2[wr + dx + 1];
          m2[oi].x += w * a[4 + 0 + 2 * dx]; m2[oi].y += w * a[4 + 1 + 2 * dx];
          m2[oi].z += w * a[4 + 2 + 2 * dx]; m2[oi].w += w * a[4 + 3 + 2 * dx];
        }
      }
      if (dd == -3 || dd == 0 || dd == 3){
        const int wr = (dd / 3 + 1) * 3;
        #pragma unroll
        for (int dx = -1; dx <= 1; ++dx){
          const float w = w3[wr + dx + 1];
          m3[oi].x += w * a[4 + 0 + 3 * dx]; m3[oi].y += w * a[4 + 1 + 3 * dx];
          m3[oi].z += w * a[4 + 2 + 3 * dx]; m3[oi].w += w * a[4 + 3 + 3 * dx];
        }
      }
      if (dd == 0) Ac[oi] = make_float4(a[4], a[5], a[6], a[7]);
    }
  }

  // ---- PT-plane (rows i0-1 .. i0+4) ----
  #pragma unroll
  for (int lr = 0; lr < 6; ++lr){
    const int ar = i0 - 1 + lr;
    const unsigned* rowP = ((unsigned)ar < 256u) ? (const unsigned*)(img + (size_t)ar * ROWB + 1056)
                                                 : (const unsigned*)zrowf;
    const uint4 ua = *(const uint4*)(rowP + j0);
    const uint4 ub = *(const uint4*)(rowP + j0 + 4);
    const uint4 uc = *(const uint4*)(rowP + j0 + 8);
    const unsigned uu[12] = {ua.x, ua.y, ua.z, ua.w, ub.x, ub.y, ub.z, ub.w, uc.x, uc.y, uc.z, uc.w};
    float p[12], t[12];
    #pragma unroll
    for (int k = 0; k < 12; ++k){
      const float2 pt = unpackh2(__builtin_bit_cast(float, uu[k]));
      p[k] = pt.x; t[k] = pt.y;
    }
    #pragma unroll
    for (int oi = 0; oi < 4; ++oi){
      const int dd = lr - 1 - oi;
      if (dd >= -1 && dd <= 1){
        const int wr = (dd + 1) * 3;
        #pragma unroll
        for (int dx = -1; dx <= 1; ++dx){
          const float wp = pw9[wr + dx + 1], wt = tw9[wr + dx + 1];
          ap[oi].x += wp * p[4 + 0 + dx]; ap[oi].y += wp * p[4 + 1 + dx];
          ap[oi].z += wp * p[4 + 2 + dx]; ap[oi].w += wp * p[4 + 3 + dx];
          at[oi].x += wt * t[4 + 0 + dx]; at[oi].y += wt * t[4 + 1 + dx];
          at[oi].z += wt * t[4 + 2 + dx]; at[oi].w += wt * t[4 + 3 + dx];
        }
      }
      if (dd == 0) Tc[oi] = make_float4(t[4], t[5], t[6], t[7]);
    }
  }

  // ---- epilogue ----
  const float gwb = gwp[z];
  const float inv_p = phase_gamma[0] * rsqrtf(phase_var[0] + 1e-5f);
  const float pmean = phase_mean[0], pbeta = phase_beta[0];
  const float f0 = fin_w[0], f1 = fin_w[1], f2 = fin_w[2];
  const float f3 = fin_w[3], f4 = fin_w[4], f5 = fin_w[5];
  const float fb = fin_b[0];
  const float inv_f = fin_gamma[0] * rsqrtf(fin_var[0] + 1e-5f);
  const float fmean = fin_mean[0], fbeta = fin_beta[0];

  #pragma unroll
  for (int oi = 0; oi < 4; ++oi){
    const float mm1[4] = {m1[oi].x, m1[oi].y, m1[oi].z, m1[oi].w};
    const float mm2[4] = {m2[oi].x, m2[oi].y, m2[oi].z, m2[oi].w};
    const float mm3[4] = {m3[oi].x, m3[oi].y, m3[oi].z, m3[oi].w};
    const float tt[4]  = {at[oi].x, at[oi].y, at[oi].z, at[oi].w};
    const float pp[4]  = {ap[oi].x, ap[oi].y, ap[oi].z, ap[oi].w};
    const float ac[4]  = {Ac[oi].x, Ac[oi].y, Ac[oi].z, Ac[oi].w};
    const float tc[4]  = {Tc[oi].x, Tc[oi].y, Tc[oi].z, Tc[oi].w};
    float o4[4];
    #pragma unroll
    for (int oj = 0; oj < 4; ++oj){
      const float Gt = tc[oj] * frcp(1.f + __expf(-tt[oj]));
      const float Pp = fmaxf((pp[oj] - pmean) * inv_p + pbeta, 0.f);
      const float pre = f0 * ac[oj] + f1 * Pp + f2 * Gt
                      + gwb * (f3 * mm1[oj] + f4 * mm2[oj] + f5 * mm3[oj]) + fb;
      float o = (pre - fmean) * inv_f + fbeta;
      o4[oj] = fminf(fmaxf(o, 0.f), 1.f);
    }
    *(float4*)(out + ((size_t)(z * 256 + i0 + oi) << 8) + j0) = make_float4(o4[0], o4[1], o4[2], o4[3]);
  }
}

extern "C" void kernel_launch(void* const* d_in, const int* in_sizes, int n_in,
                              void* d_out, int out_size, void* d_ws, size_t ws_size,
                              hipStream_t stream){
  const float* x  = (const float*)d_in[0];
  const float* km = (const float*)d_in[1];

  // layout: [arena: imgsPer*IMGB] [zrow 2112] [sTabS 262144] [gw 1024] [rowsum rowsPer*4]
  int N = 1;
  while (N < 64){
    const size_t need = (size_t)(256 / N) * IMGB + 2112ull + 262144ull + 1024ull
                      + (size_t)(256 / N) * 1024ull;
    if (need <= ws_size) break;
    N <<= 1;
  }
  const int imgsPer = 256 / N;
  const int rowsPer = imgsPer * 256;

  char*  ws     = (char*)d_ws;
  char*  arena  = ws;
  float* zrow   = (float*)(ws + (size_t)imgsPer * IMGB);
  float* sTabS  = (float*)(ws + (size_t)imgsPer * IMGB + 2112ull);
  float* gwbuf  = (float*)(ws + (size_t)imgsPer * IMGB + 2112ull + 262144ull);
  float* rowsum = (float*)(ws + (size_t)imgsPer * IMGB + 2112ull + 262144ull + 1024ull);

  k0_prep<<<256, 256, 0, stream>>>(km, sTabS, zrow);

  for (int s = 0; s < N; ++s){
    const float* xs = x + (size_t)s * rowsPer * 256;
    float* outs = (float*)d_out + (size_t)s * rowsPer * 256;

    k1_row<<<rowsPer / 8, 256, 0, stream>>>(xs, arena);
    k2_col<<<imgsPer * 32, 512, 0, stream>>>(arena, sTabS);
    k3_rowinv<<<rowsPer / 4, 256, 0, stream>>>(xs, arena,
        (const float*)d_in[10], (const float*)d_in[11], rowsum);
    kpad<<<imgsPer, 256, 0, stream>>>(arena);
    k4_gw<<<imgsPer, 256, 0, stream>>>(rowsum,
        (const float*)d_in[18], (const float*)d_in[19],
        (const float*)d_in[20], (const float*)d_in[21], gwbuf);
    k5_fuse<<<dim3(4, 4, imgsPer), 256, 0, stream>>>(
        arena, zrow, gwbuf,
        (const float*)d_in[2],  (const float*)d_in[3],
        (const float*)d_in[4],  (const float*)d_in[5],
        (const float*)d_in[6],  (const float*)d_in[7],
        (const float*)d_in[8],  (const float*)d_in[9],
        (const float*)d_in[12], (const float*)d_in[13],
        (const float*)d_in[14], (const float*)d_in[15],
        (const float*)d_in[16], (const float*)d_in[17],
        (const float*)d_in[22], (const float*)d_in[23],
        (const float*)d_in[24], (const float*)d_in[25],
        (const float*)d_in[26], (const float*)d_in[27],
        outs);
  }
}

// Round 15
// 356.048 us; speedup vs baseline: 1.1137x; 1.0333x over previous
//
#include <hip/hip_runtime.h>
#include <hip/hip_fp16.h>
#include <math.h>

#define PI_F 3.14159265358979323846f
#define ROWB 2112ull            // bytes per arena row
#define IMGB (ROWB * 256ull)    // 540672 bytes per image

__device__ __forceinline__ unsigned rev8(unsigned v){ return __brev(v) >> 24; }

__device__ __forceinline__ float2 cmulf(float2 a, float2 b){ return make_float2(a.x*b.x - a.y*b.y, a.x*b.y + a.y*b.x); }
__device__ __forceinline__ float2 cmulc(float2 a, float2 b){ return make_float2(a.x*b.x + a.y*b.y, a.y*b.x - a.x*b.y); } // a*conj(b)
__device__ __forceinline__ float2 cadd (float2 a, float2 b){ return make_float2(a.x+b.x, a.y+b.y); }
__device__ __forceinline__ float2 csub (float2 a, float2 b){ return make_float2(a.x-b.x, a.y-b.y); }
__device__ __forceinline__ float2 eix(float a){ float s, c; __sincosf(a, &s, &c); return make_float2(c, s); }

__device__ __forceinline__ float frcp(float x){ float r; asm("v_rcp_f32 %0, %1" : "=v"(r) : "v"(x)); return r; }

// XOR-shuffle primitive: ds_swizzle (immediate pattern, no addr setup) for d<32,
// __shfl_xor (bpermute) only for the half-crossing d=32. Bit-identical semantics.
template<int D>
__device__ __forceinline__ float sw1(float v){
  if constexpr (D < 32){
    return __builtin_bit_cast(float,
      __builtin_amdgcn_ds_swizzle(__builtin_bit_cast(int, v), (D << 10) | 0x1F));
  } else {
    return __shfl_xor(v, 32);
  }
}
template<int D>
__device__ __forceinline__ float2 sxc(float2 v){
  return make_float2(sw1<D>(v.x), sw1<D>(v.y));
}

// atan2(y,x) for y > 0 (result in (0, pi)). Deg-11 odd minimax, err ~2e-6 rad.
__device__ __forceinline__ float fast_atan2pos(float y, float x){
  const float ax = fabsf(x);
  const float mn = fminf(ax, y), mx = fmaxf(ax, y);
  const float t  = mn * frcp(mx);
  const float z  = t * t;
  float p = -0.01172120f;
  p = fmaf(p, z,  0.05265332f);
  p = fmaf(p, z, -0.11643287f);
  p = fmaf(p, z,  0.19354346f);
  p = fmaf(p, z, -0.33262347f);
  p = fmaf(p, z,  0.99997726f);
  p = p * t;
  p = (y > ax) ? (1.57079632679f - p) : p;
  p = (x < 0.f) ? (3.14159265359f - p) : p;
  return p;
}

__device__ __forceinline__ unsigned packh2u(float a, float b){
  return __builtin_bit_cast(unsigned, __floats2half2_rn(a, b));
}
__device__ __forceinline__ float2 unpackh2(float p){
  return __half22float2(__builtin_bit_cast(__half2, p));
}

// Per-lane twiddles (forward sign e^{-i...}).
struct Twid { float2 w, w2, t[6]; };
__device__ __forceinline__ void mktw(Twid& T, int lane){
  T.w  = eix(-(2.0f * PI_F / 256.0f) * (float)lane);
  T.w2 = cmulf(T.w, T.w);
  #pragma unroll
  for (int st = 0; st < 6; ++st){
    const int d = 32 >> st;
    T.t[st] = eix(-(PI_F / (float)d) * (float)(lane & (d - 1)));  // W_{2d}^{lane mod d}
  }
}

// radix-4 head of forward DIF (per stream).
__device__ __forceinline__ void fwd_head(float2 v[4], const Twid& T){
  const float2 t0 = cadd(v[0], v[2]);
  const float2 b0 = cmulf(csub(v[0], v[2]), T.w);
  const float2 t1 = cadd(v[1], v[3]);
  const float2 w64 = make_float2(T.w.y, -T.w.x);           // w * (-i)
  const float2 b1 = cmulf(csub(v[1], v[3]), w64);
  v[0] = cadd(t0, t1);
  v[1] = cmulf(csub(t0, t1), T.w2);
  v[2] = cadd(b0, b1);
  v[3] = cmulf(csub(b0, b1), T.w2);
}
// radix-4 tail of inverse DIT (per stream).
__device__ __forceinline__ void inv_tail(float2 v[4], const Twid& T){
  const float2 uci = make_float2(T.w.y, T.w.x);             // conj(w)*i
  const float2 m1 = cmulc(v[1], T.w2);
  const float2 m3a = cmulc(v[3], T.w2);
  const float2 n0 = cadd(v[0], m1), n1 = csub(v[0], m1);
  const float2 n2 = cadd(v[2], m3a), n3 = csub(v[2], m3a);
  const float2 m2 = cmulc(n2, T.w);
  const float2 m3 = cmulf(n3, uci);
  v[0] = cadd(n0, m2); v[2] = csub(n0, m2);
  v[1] = cadd(n1, m3); v[3] = csub(n1, m3);
}

// Hoisted-coefficient butterfly: out = v*A + p*B (complex). 8 VALU ops.
__device__ __forceinline__ float2 stage_ab(float2 v, float2 p, float Ax, float Ay, float Bx, float By){
  float2 o;
  o.x = v.x*Ax - v.y*Ay + p.x*Bx - p.y*By;
  o.y = v.x*Ay + v.y*Ax + p.x*By + p.y*Bx;
  return o;
}

// ---------- SELECT-FORM FFTs (k2; r12/r14-proven VGPR profile) ----------
__device__ __forceinline__ void fft256_fwd_sel(float2 v[4], int lane, const Twid& T){
  fwd_head(v, T);
#define FWDS_STAGE(ST) { \
  constexpr int d = 32 >> (ST); \
  const float2 tw = T.t[ST]; \
  const bool hi = (lane & d) != 0; \
  for (int s = 0; s < 4; ++s){ \
    const float2 p = sxc<d>(v[s]); \
    const float2 bo = cmulf(csub(p, v[s]), tw); \
    const float2 lo = cadd(v[s], p); \
    v[s] = hi ? bo : lo; \
  } }
  FWDS_STAGE(0) FWDS_STAGE(1) FWDS_STAGE(2) FWDS_STAGE(3) FWDS_STAGE(4) FWDS_STAGE(5)
#undef FWDS_STAGE
}
__device__ __forceinline__ void fft256_inv2_sel(float2 a[4], float2 b[4], int lane, const Twid& T){
#define INVS_STAGE(ST) { \
  constexpr int d = 1 << (ST); \
  const float2 tw = T.t[5 - (ST)]; \
  const bool hi = (lane & d) != 0; \
  for (int s = 0; s < 4; ++s){ \
    const float2 pa = sxc<d>(a[s]); \
    const float2 pb = sxc<d>(b[s]); \
    const float2 ma = cmulc(hi ? a[s] : pa, tw); \
    const float2 mb = cmulc(hi ? b[s] : pb, tw); \
    a[s] = hi ? csub(pa, ma) : cadd(a[s], ma); \
    b[s] = hi ? csub(pb, mb) : cadd(b[s], mb); \
  } }
  INVS_STAGE(0) INVS_STAGE(1) INVS_STAGE(2) INVS_STAGE(3) INVS_STAGE(4) INVS_STAGE(5)
#undef INVS_STAGE
  inv_tail(a, T);
  inv_tail(b, T);
}

// ---------- HOISTED-FORM FFTs (k1/k3) ----------
__device__ __forceinline__ void fft256_fwd2(float2 a[4], float2 b[4], int lane, const Twid& T){
  fwd_head(a, T);
  fwd_head(b, T);
#define FWD2_STAGE(ST) { \
  constexpr int d = 32 >> (ST); \
  const float2 t = T.t[ST]; \
  const bool hi = (lane & d) != 0; \
  const float Ax = hi ? -t.x : 1.f, Ay = hi ? -t.y : 0.f; \
  const float Bx = hi ?  t.x : 1.f, By = hi ?  t.y : 0.f; \
  for (int s = 0; s < 4; ++s){ \
    const float2 pa = sxc<d>(a[s]); \
    const float2 pb = sxc<d>(b[s]); \
    a[s] = stage_ab(a[s], pa, Ax, Ay, Bx, By); \
    b[s] = stage_ab(b[s], pb, Ax, Ay, Bx, By); \
  } }
  FWD2_STAGE(0) FWD2_STAGE(1) FWD2_STAGE(2) FWD2_STAGE(3) FWD2_STAGE(4) FWD2_STAGE(5)
#undef FWD2_STAGE
}
// lo: out = v + p*conj(t) -> A=(1,0), B=(t.x,-t.y); hi: out = p - v*conj(t) -> A=(-t.x,t.y), B=(1,0)
__device__ __forceinline__ void fft256_inv2(float2 a[4], float2 b[4], int lane, const Twid& T){
#define INV2_STAGE(ST) { \
  constexpr int d = 1 << (ST); \
  const float2 t = T.t[5 - (ST)]; \
  const bool hi = (lane & d) != 0; \
  const float Ax = hi ? -t.x : 1.f, Ay = hi ?  t.y : 0.f; \
  const float Bx = hi ?  1.f : t.x, By = hi ?  0.f : -t.y; \
  for (int s = 0; s < 4; ++s){ \
    const float2 pa = sxc<d>(a[s]); \
    const float2 pb = sxc<d>(b[s]); \
    a[s] = stage_ab(a[s], pa, Ax, Ay, Bx, By); \
    b[s] = stage_ab(b[s], pb, Ax, Ay, Bx, By); \
  } }
  INV2_STAGE(0) INV2_STAGE(1) INV2_STAGE(2) INV2_STAGE(3) INV2_STAGE(4) INV2_STAGE(5)
#undef INV2_STAGE
  inv_tail(a, T);
  inv_tail(b, T);
}

// K0: scrambled Riesz scale table + zero row.
__global__ __launch_bounds__(256) void k0_prep(const float* __restrict__ km,
                                               float* __restrict__ sTabS,
                                               float* __restrict__ zrow){
  const int idx = blockIdx.x * 256 + threadIdx.x;
  const int q = idx >> 8, r = idx & 255;
  const int u = rev8(q), v = rev8(r);
  const float kv = km[u * 256 + v];
  float sp = fmaxf(kv, 0.f) + log1pf(expf(-fabsf(kv)));
  sp = fminf(fmaxf(sp, 1e-3f), 10.f);
  const float fu = (float)(u + 1), fv = (float)(v + 1);
  sTabS[idx] = sp / (sqrtf(fu * fu + fv * fv) + 1e-6f) * (1.0f / 65536.0f);
  if (blockIdx.x == 0){
    zrow[threadIdx.x] = 0.f;
    zrow[threadIdx.x + 256] = 0.f;
    if (threadIdx.x < 16) zrow[threadIdx.x + 512] = 0.f;
  }
}

// K1: forward row FFT. 2 rows per wave (hoisted dual), 8 rows/block.
__global__ __launch_bounds__(256) void k1_row(const float* __restrict__ x, char* __restrict__ arena){
  const int grp = threadIdx.x >> 6, lane = threadIdx.x & 63;
  const int rs = blockIdx.x * 8 + grp * 2;
  Twid T; mktw(T, lane);
  const float* xr0 = x + (size_t)rs * 256;
  const float* xr1 = xr0 + 256;
  float2 a[4], b[4];
  #pragma unroll
  for (int s = 0; s < 4; ++s){
    a[s] = make_float2(xr0[lane + 64 * s], 0.f);
    b[s] = make_float2(xr1[lane + 64 * s], 0.f);
  }
  fft256_fwd2(a, b, lane, T);
  float2* S0 = (float2*)(arena + (size_t)rs * ROWB);
  float2* S1 = (float2*)(arena + (size_t)(rs + 1) * ROWB);
  #pragma unroll
  for (int s = 0; s < 4; ++s){ S0[lane + 64 * s] = a[s]; S1[lane + 64 * s] = b[s]; }
}

// K2: per (image, 8-col tile): col FFT, both Riesz filters, dual col IFFT; packed fp16 in place.
// 512 threads = 8 waves, ONE column per wave. Select-form FFTs; 9-pitch swizzled LDS;
// wave-private column slots -> in-place writeback. ONLY change vs r14: swizzle primitive.
__global__ __launch_bounds__(512) void k2_col(char* __restrict__ arena, const float* __restrict__ sTabS){
  __shared__ float2 lds[256 * 9];
  const int tid = threadIdx.x;
  const int b  = blockIdx.x >> 5;
  const int u0 = (blockIdx.x & 31) << 3;
  char* base = arena + (size_t)b * IMGB;

  #pragma unroll
  for (int k = 0; k < 4; ++k){
    const int idx = tid + (k << 9);
    const int r = idx >> 3, cc = idx & 7;
    lds[r * 9 + (cc ^ ((r >> 3) & 7))] = *(const float2*)(base + (size_t)r * ROWB + (size_t)(u0 + cc) * 8);
  }
  __syncthreads();

  const int wv = tid >> 6, lane = tid & 63;
  Twid T; mktw(T, lane);
  const int r6 = __brev(lane) >> 26;                 // rev6(lane)
  float fvv[4];
  fvv[0] = (float)(4 * r6 + 0 + 1);
  fvv[1] = (float)(4 * r6 + 2 + 1);
  fvv[2] = (float)(4 * r6 + 1 + 1);
  fvv[3] = (float)(4 * r6 + 3 + 1);
  const int swb = (lane >> 3) & 7;

  {
    const int c = wv;                                // one column per wave
    const int q = u0 + c;
    const int swc = c ^ swb;
    float2 F[4];
    #pragma unroll
    for (int s = 0; s < 4; ++s) F[s] = lds[(lane + 64 * s) * 9 + swc];
    fft256_fwd_sel(F, lane, T);
    float sc[4];
    #pragma unroll
    for (int s = 0; s < 4; ++s) sc[s] = sTabS[q * 256 + lane + 64 * s];
    const float fu = (float)(rev8((unsigned)q) + 1);
    float2 G1[4], G2[4];
    #pragma unroll
    for (int s = 0; s < 4; ++s){
      const float a1 = fvv[s] * sc[s];
      const float a2 = fu * sc[s];
      G1[s] = make_float2(a1 * F[s].y, -a1 * F[s].x);
      G2[s] = make_float2(a2 * F[s].y, -a2 * F[s].x);
    }
    fft256_inv2_sel(G1, G2, lane, T);
    #pragma unroll
    for (int s = 0; s < 4; ++s)
      lds[(lane + 64 * s) * 9 + swc] =
          make_float2(__uint_as_float(packh2u(G1[s].x, G1[s].y)),
                      __uint_as_float(packh2u(G2[s].x, G2[s].y)));
  }
  __syncthreads();
  #pragma unroll
  for (int k = 0; k < 4; ++k){
    const int idx = tid + (k << 9);
    const int r = idx >> 3, cc = idx & 7;
    *(float2*)(base + (size_t)r * ROWB + (size_t)(u0 + cc) * 8) = lds[r * 9 + (cc ^ ((r >> 3) & 7))];
  }
}

// K3: dual row IFFT of packed U1/U2 + pointwise; writes A (fp16!) + PT (h2) in place over SPEC rows.
// Row layout after k3: [0,8) A-halo, [8,520) A h2, [520,528) A-halo, [1064,1072) PT-halo,
// [1072,2096) PT h2(P,T), [2096,2104) PT-halo. Halo zeroing folded in (kpad kernel removed).
__global__ __launch_bounds__(256) void k3_rowinv(const float* __restrict__ x, char* __restrict__ arena,
    const float* __restrict__ ampw, const float* __restrict__ ampb,
    float* __restrict__ rowsum){
  const int grp = threadIdx.x >> 6, lane = threadIdx.x & 63;
  const int rs = blockIdx.x * 4 + grp;
  Twid T; mktw(T, lane);
  char* rowb = arena + (size_t)rs * ROWB;
  float2 g1[4], g2[4];
  #pragma unroll
  for (int s = 0; s < 4; ++s){
    const float2 pk = *(const float2*)(rowb + (size_t)(lane + 64 * s) * 8);
    g1[s] = unpackh2(pk.x); g2[s] = unpackh2(pk.y);
  }
  fft256_inv2(g1, g2, lane, T);
  const float aw = *ampw, ab = *ampb;
  const float* xr = x + (size_t)rs * 256;
  __half* Arow = (__half*)(rowb + 8);
  unsigned* Prow = (unsigned*)(rowb + 1072);
  float sum = 0.f;
  #pragma unroll
  for (int s = 0; s < 4; ++s){
    const int j = lane + 64 * s;
    const float xv = xr[j];
    const float R1 = sqrtf(fmaf(g1[s].x, g1[s].x, g1[s].y * g1[s].y)) + 1e-6f;
    const float R2 = sqrtf(fmaf(g2[s].x, g2[s].x, g2[s].y * g2[s].y)) + 1e-6f;
    const float rr = fmaf(R1, R1, R2 * R2);
    const float A = sqrtf(fmaxf(fmaf(xv, xv, rr), 0.f) + 1e-6f);
    const float P  = fast_atan2pos(sqrtf(rr) + 1e-6f, xv + 1e-6f);
    const float Th = fast_atan2pos(R2, R1 + 1e-6f);
    const float Ab = A + fmaxf(fmaf(aw, A, ab), 0.f);
    Arow[j] = __float2half_rn(Ab);
    Prow[j] = packh2u(P, Th);
    sum += Ab;
  }
  #pragma unroll
  for (int off = 32; off; off >>= 1) sum += __shfl_down(sum, off);
  if (lane == 0) rowsum[rs] = sum;
  // folded halo zeroing (was kpad): 4 disjoint 8-byte quads per row
  if (lane < 4){
    const size_t off8 = (lane == 0) ? 0ull : (lane == 1) ? 520ull : (lane == 2) ? 1064ull : 2096ull;
    *(unsigned long long*)(rowb + off8) = 0ull;
  }
}

// K4: per-image gate from 256 row sums.
__global__ __launch_bounds__(256) void k4_gw(const float* __restrict__ rowsum,
    const float* __restrict__ fc1w, const float* __restrict__ fc1b,
    const float* __restrict__ fc2w, const float* __restrict__ fc2b,
    float* __restrict__ gw){
  __shared__ float red[256];
  const int tid = threadIdx.x;
  red[tid] = rowsum[blockIdx.x * 256 + tid];
  __syncthreads();
  #pragma unroll
  for (int off = 128; off; off >>= 1){
    if (tid < off) red[tid] += red[tid + off];
    __syncthreads();
  }
  if (tid == 0){
    const float gf = red[0] * (1.0f / 65536.0f);
    float acc = fc2b[0];
    #pragma unroll
    for (int k = 0; k < 16; ++k)
      acc += fc2w[k] * fmaxf(gf * fc1w[k] + fc1b[k], 0.f);
    gw[blockIdx.x] = frcp(1.f + __expf(-acc));
  }
}

// K5: register-blocked 4x4/thread convs + fusion; A plane now fp16; row-halo via zero-row pointer.
__global__ __launch_bounds__(256) void k5_fuse(
    const char* __restrict__ arena, const float* __restrict__ zrowf,
    const float* __restrict__ gwp,
    const float* __restrict__ theta_w, const float* __restrict__ theta_b,
    const float* __restrict__ phase_w, const float* __restrict__ phase_b,
    const float* __restrict__ phase_gamma, const float* __restrict__ phase_beta,
    const float* __restrict__ phase_mean, const float* __restrict__ phase_var,
    const float* __restrict__ ms_w1, const float* __restrict__ ms_b1,
    const float* __restrict__ ms_w2, const float* __restrict__ ms_b2,
    const float* __restrict__ ms_w3, const float* __restrict__ ms_b3,
    const float* __restrict__ fin_w, const float* __restrict__ fin_b,
    const float* __restrict__ fin_gamma, const float* __restrict__ fin_beta,
    const float* __restrict__ fin_mean, const float* __restrict__ fin_var,
    float* __restrict__ out){
  const int z = blockIdx.z;
  const int tx = threadIdx.x & 15, ty = threadIdx.x >> 4;
  const int j0 = (blockIdx.x << 6) + (tx << 2);
  const int i0 = (blockIdx.y << 6) + (ty << 2);
  const char* img = arena + (size_t)z * IMGB;

  float tw9[9], pw9[9], w1[9], w2[9], w3[9];
  #pragma unroll
  for (int k = 0; k < 9; ++k){
    tw9[k] = theta_w[k]; pw9[k] = phase_w[k];
    w1[k] = ms_w1[k]; w2[k] = ms_w2[k]; w3[k] = ms_w3[k];
  }
  const float b1s = ms_b1[0], b2s = ms_b2[0], b3s = ms_b3[0];
  const float tbs = theta_b[0], pbs = phase_b[0];

  float4 m1[4], m2[4], m3[4], at[4], ap[4], Ac[4], Tc[4];
  #pragma unroll
  for (int oi = 0; oi < 4; ++oi){
    m1[oi] = make_float4(b1s, b1s, b1s, b1s);
    m2[oi] = make_float4(b2s, b2s, b2s, b2s);
    m3[oi] = make_float4(b3s, b3s, b3s, b3s);
    at[oi] = make_float4(tbs, tbs, tbs, tbs);
    ap[oi] = make_float4(pbs, pbs, pbs, pbs);
  }

  // ---- A-plane (fp16; rows i0-3 .. i0+6, cols j0-4 .. j0+7) ----
  #pragma unroll
  for (int lr = 0; lr < 10; ++lr){
    const int ar = i0 - 3 + lr;
    const __half* rowA = ((unsigned)ar < 256u) ? (const __half*)(img + (size_t)ar * ROWB + 8)
                                               : ((const __half*)zrowf + 4);
    const uint2 h0 = *(const uint2*)(rowA + (j0 - 4));
    const uint2 h1 = *(const uint2*)(rowA + j0);
    const uint2 h2v = *(const uint2*)(rowA + (j0 + 4));
    float a[12];
    {
      const float2 p0 = unpackh2(__builtin_bit_cast(float, h0.x));
      const float2 p1 = unpackh2(__builtin_bit_cast(float, h0.y));
      const float2 p2 = unpackh2(__builtin_bit_cast(float, h1.x));
      const float2 p3 = unpackh2(__builtin_bit_cast(float, h1.y));
      const float2 p4 = unpackh2(__builtin_bit_cast(float, h2v.x));
      const float2 p5 = unpackh2(__builtin_bit_cast(float, h2v.y));
      a[0]=p0.x; a[1]=p0.y; a[2]=p1.x; a[3]=p1.y;
      a[4]=p2.x; a[5]=p2.y; a[6]=p3.x; a[7]=p3.y;
      a[8]=p4.x; a[9]=p4.y; a[10]=p5.x; a[11]=p5.y;
    }
    #pragma unroll
    for (int oi = 0; oi < 4; ++oi){
      const int dd = lr - 3 - oi;
      if (dd >= -1 && dd <= 1){
        const int wr = (dd + 1) * 3;
        #pragma unroll
        for (int dx = -1; dx <= 1; ++dx){
          const float w = w1[wr + dx + 1];
          m1[oi].x += w * a[4 + 0 + dx]; m1[oi].y += w * a[4 + 1 + dx];
          m1[oi].z += w * a[4 + 2 + dx]; m1[oi].w += w * a[4 + 3 + dx];
        }
      }
      if (dd == -2 || dd == 0 || dd == 2){
        const int wr = (dd / 2 + 1) * 3;
        #pragma unroll
        for (int dx = -1; dx <= 1; ++dx){
          const float w = w2[wr + dx + 1];
          m2[oi].x += w * a[4 + 0 + 2 * dx]; m2[oi].y += w * a[4 + 1 + 2 * dx];
          m2[oi].z += w * a[4 + 2 + 2 * dx]; m2[oi].w += w * a[4 + 3 + 2 * dx];
        }
      }
      if (dd == -3 || dd == 0 || dd == 3){
        const int wr = (dd / 3 + 1) * 3;
        #pragma unroll
        for (int dx = -1; dx <= 1; ++dx){
          const float w = w3[wr + dx + 1];
          m3[oi].x += w * a[4 + 0 + 3 * dx]; m3[oi].y += w * a[4 + 1 + 3 * dx];
          m3[oi].z += w * a[4 + 2 + 3 * dx]; m3[oi].w += w * a[4 + 3 + 3 * dx];
        }
      }
      if (dd == 0) Ac[oi] = make_float4(a[4], a[5], a[6], a[7]);
    }
  }

  // ---- PT-plane (rows i0-1 .. i0+4) ----
  #pragma unroll
  for (int lr = 0; lr < 6; ++lr){
    const int ar = i0 - 1 + lr;
    const unsigned* rowP = ((unsigned)ar < 256u) ? (const unsigned*)(img + (size_t)ar * ROWB + 1056)
                                                 : (const unsigned*)zrowf;
    const uint4 ua = *(const uint4*)(rowP + j0);
    const uint4 ub = *(const uint4*)(rowP + j0 + 4);
    const uint4 uc = *(const uint4*)(rowP + j0 + 8);
    const unsigned uu[12] = {ua.x, ua.y, ua.z, ua.w, ub.x, ub.y, ub.z, ub.w, uc.x, uc.y, uc.z, uc.w};
    float p[12], t[12];
    #pragma unroll
    for (int k = 0; k < 12; ++k){
      const float2 pt = unpackh2(__builtin_bit_cast(float, uu[k]));
      p[k] = pt.x; t[k] = pt.y;
    }
    #pragma unroll
    for (int oi = 0; oi < 4; ++oi){
      const int dd = lr - 1 - oi;
      if (dd >= -1 && dd <= 1){
        const int wr = (dd + 1) * 3;
        #pragma unroll
        for (int dx = -1; dx <= 1; ++dx){
          const float wp = pw9[wr + dx + 1], wt = tw9[wr + dx + 1];
          ap[oi].x += wp * p[4 + 0 + dx]; ap[oi].y += wp * p[4 + 1 + dx];
          ap[oi].z += wp * p[4 + 2 + dx]; ap[oi].w += wp * p[4 + 3 + dx];
          at[oi].x += wt * t[4 + 0 + dx]; at[oi].y += wt * t[4 + 1 + dx];
          at[oi].z += wt * t[4 + 2 + dx]; at[oi].w += wt * t[4 + 3 + dx];
        }
      }
      if (dd == 0) Tc[oi] = make_float4(t[4], t[5], t[6], t[7]);
    }
  }

  // ---- epilogue ----
  const float gwb = gwp[z];
  const float inv_p = phase_gamma[0] * rsqrtf(phase_var[0] + 1e-5f);
  const float pmean = phase_mean[0], pbeta = phase_beta[0];
  const float f0 = fin_w[0], f1 = fin_w[1], f2 = fin_w[2];
  const float f3 = fin_w[3], f4 = fin_w[4], f5 = fin_w[5];
  const float fb = fin_b[0];
  const float inv_f = fin_gamma[0] * rsqrtf(fin_var[0] + 1e-5f);
  const float fmean = fin_mean[0], fbeta = fin_beta[0];

  #pragma unroll
  for (int oi = 0; oi < 4; ++oi){
    const float mm1[4] = {m1[oi].x, m1[oi].y, m1[oi].z, m1[oi].w};
    const float mm2[4] = {m2[oi].x, m2[oi].y, m2[oi].z, m2[oi].w};
    const float mm3[4] = {m3[oi].x, m3[oi].y, m3[oi].z, m3[oi].w};
    const float tt[4]  = {at[oi].x, at[oi].y, at[oi].z, at[oi].w};
    const float pp[4]  = {ap[oi].x, ap[oi].y, ap[oi].z, ap[oi].w};
    const float ac[4]  = {Ac[oi].x, Ac[oi].y, Ac[oi].z, Ac[oi].w};
    const float tc[4]  = {Tc[oi].x, Tc[oi].y, Tc[oi].z, Tc[oi].w};
    float o4[4];
    #pragma unroll
    for (int oj = 0; oj < 4; ++oj){
      const float Gt = tc[oj] * frcp(1.f + __expf(-tt[oj]));
      const float Pp = fmaxf((pp[oj] - pmean) * inv_p + pbeta, 0.f);
      const float pre = f0 * ac[oj] + f1 * Pp + f2 * Gt
                      + gwb * (f3 * mm1[oj] + f4 * mm2[oj] + f5 * mm3[oj]) + fb;
      float o = (pre - fmean) * inv_f + fbeta;
      o4[oj] = fminf(fmaxf(o, 0.f), 1.f);
    }
    *(float4*)(out + ((size_t)(z * 256 + i0 + oi) << 8) + j0) = make_float4(o4[0], o4[1], o4[2], o4[3]);
  }
}

extern "C" void kernel_launch(void* const* d_in, const int* in_sizes, int n_in,
                              void* d_out, int out_size, void* d_ws, size_t ws_size,
                              hipStream_t stream){
  const float* x  = (const float*)d_in[0];
  const float* km = (const float*)d_in[1];

  // layout: [arena: imgsPer*IMGB] [zrow 2112] [sTabS 262144] [gw 1024] [rowsum rowsPer*4]
  int N = 1;
  while (N < 64){
    const size_t need = (size_t)(256 / N) * IMGB + 2112ull + 262144ull + 1024ull
                      + (size_t)(256 / N) * 1024ull;
    if (need <= ws_size) break;
    N <<= 1;
  }
  const int imgsPer = 256 / N;
  const int rowsPer = imgsPer * 256;

  char*  ws     = (char*)d_ws;
  char*  arena  = ws;
  float* zrow   = (float*)(ws + (size_t)imgsPer * IMGB);
  float* sTabS  = (float*)(ws + (size_t)imgsPer * IMGB + 2112ull);
  float* gwbuf  = (float*)(ws + (size_t)imgsPer * IMGB + 2112ull + 262144ull);
  float* rowsum = (float*)(ws + (size_t)imgsPer * IMGB + 2112ull + 262144ull + 1024ull);

  k0_prep<<<256, 256, 0, stream>>>(km, sTabS, zrow);

  for (int s = 0; s < N; ++s){
    const float* xs = x + (size_t)s * rowsPer * 256;
    float* outs = (float*)d_out + (size_t)s * rowsPer * 256;

    k1_row<<<rowsPer / 8, 256, 0, stream>>>(xs, arena);
    k2_col<<<imgsPer * 32, 512, 0, stream>>>(arena, sTabS);
    k3_rowinv<<<rowsPer / 4, 256, 0, stream>>>(xs, arena,
        (const float*)d_in[10], (const float*)d_in[11], rowsum);
    k4_gw<<<imgsPer, 256, 0, stream>>>(rowsum,
        (const float*)d_in[18], (const float*)d_in[19],
        (const float*)d_in[20], (const float*)d_in[21], gwbuf);
    k5_fuse<<<dim3(4, 4, imgsPer), 256, 0, stream>>>(
        arena, zrow, gwbuf,
        (const float*)d_in[2],  (const float*)d_in[3],
        (const float*)d_in[4],  (const float*)d_in[5],
        (const float*)d_in[6],  (const float*)d_in[7],
        (const float*)d_in[8],  (const float*)d_in[9],
        (const float*)d_in[12], (const float*)d_in[13],
        (const float*)d_in[14], (const float*)d_in[15],
        (const float*)d_in[16], (const float*)d_in[17],
        (const float*)d_in[22], (const float*)d_in[23],
        (const float*)d_in[24], (const float*)d_in[25],
        (const float*)d_in[26], (const float*)d_in[27],
        outs);
  }
}